// Round 6
// baseline (502.831 us; speedup 1.0000x reference)
//
#include <hip/hip_runtime.h>

typedef __attribute__((ext_vector_type(8))) short bf16x8;
typedef __attribute__((ext_vector_type(4))) float f32x4;
typedef unsigned short u16;

__device__ __forceinline__ u16 f2b(float f) {
  union { float f; unsigned u; } v; v.f = f;
  return (u16)((v.u + 0x7FFFu + ((v.u >> 16) & 1u)) >> 16);
}
__device__ __forceinline__ float b2f(u16 x) {
  union { unsigned u; float f; } v; v.u = (unsigned)x << 16; return v.f;
}

__device__ __forceinline__ void gload16(const void* g, void* l) {
  __builtin_amdgcn_global_load_lds((__attribute__((address_space(1))) void*)(g),
                                   (__attribute__((address_space(3))) void*)(l),
                                   16, 0, 0);
}

__device__ __forceinline__ void mbar() {
  asm volatile("" ::: "memory");
  __builtin_amdgcn_s_barrier();
  asm volatile("" ::: "memory");
}

// ---------------- batched fp32 -> bf16 (all 7 weight tensors, one launch) ----------------
__device__ __forceinline__ void cv1(const float4* __restrict__ s, u16* __restrict__ d, int i) {
  float4 v = s[i];
  unsigned long long pk = (unsigned long long)f2b(v.x) |
                          ((unsigned long long)f2b(v.y) << 16) |
                          ((unsigned long long)f2b(v.z) << 32) |
                          ((unsigned long long)f2b(v.w) << 48);
  *(unsigned long long*)(d + (size_t)i * 4) = pk;
}

__global__ __launch_bounds__(256)
void f2b_multi(const float4* s0, u16* d0, const float4* s1, u16* d1,
               const float4* s2, u16* d2, const float4* s3, u16* d3,
               const float4* s4, u16* d4, const float4* s5, u16* d5,
               const float4* s6, u16* d6) {
  int i = blockIdx.x * 256 + threadIdx.x;
  const int stride = gridDim.x * 256;
  for (; i < 5144576; i += stride) {
    int j = i;
    if (j < 196608) { cv1(s0, d0, j); continue; }
    j -= 196608;
    if (j < 65536) { cv1(s1, d1, j); continue; }
    j -= 65536;
    if (j < 196608) { cv1(s2, d2, j); continue; }
    j -= 196608;
    if (j < 65536) { cv1(s3, d3, j); continue; }
    j -= 65536;
    if (j < 262144) { cv1(s4, d4, j); continue; }
    j -= 262144;
    if (j < 262144) { cv1(s5, d5, j); continue; }
    j -= 262144;
    cv1(s6, d6, j);
  }
}

// ---------------- embedding * sqrt(D) + sinusoidal PE ----------------
__global__ __launch_bounds__(256) void embed_pe(const int* __restrict__ tok,
    const float* __restrict__ emb, float* __restrict__ xf, u16* __restrict__ xb) {
  const int s = blockIdx.x;
  const int i = threadIdx.x;
  const int t = tok[s];
  const float div = __expf((float)(2 * i) * -0.017988946039015984f);
  const float ang = (float)s * div;
  const float sv = __sinf(ang), cv = __cosf(ang);
  const float* e = emb + (size_t)t * 512 + 2 * i;
  const float x0 = e[0] * 22.627416997969522f + sv;
  const float x1 = e[1] * 22.627416997969522f + cv;
  const size_t o = (size_t)s * 512 + 2 * i;
  xf[o] = x0; xf[o + 1] = x1;
  xb[o] = f2b(x0); xb[o + 1] = f2b(x1);
}

// ---------------- tiled GEMM: C = A(MxK) . B(NxK)^T + bias; BK=64, swizzled LDS ----------------
template<int BM, int RELU, int WF32, int WB16>
__global__ __launch_bounds__(256)
void gemm_bt(const u16* __restrict__ A, const u16* __restrict__ B,
             const float* __restrict__ bias, float* __restrict__ Cf,
             u16* __restrict__ Cb, int M, int N, int K)
{
  constexpr int MFR = BM / 32;
  __shared__ __align__(16) u16 As[BM * 64];
  __shared__ __align__(16) u16 Bs[128 * 64];
  const int tid = threadIdx.x;
  const int wid = tid >> 6, lane = tid & 63;
  const int lo = lane & 15, hi = lane >> 4;
  const int nbn = N >> 7;
  const int cpx = (int)gridDim.x >> 3;
  const int bid = blockIdx.x;
  const int swz = (bid & 7) * cpx + (bid >> 3);
  const int bi = swz / nbn, bj = swz - bi * nbn;
  const size_t row0 = (size_t)bi * BM, col0 = (size_t)bj << 7;
  const int wr = (wid >> 1) * (BM / 2), wc = (wid & 1) << 6;
  const int srow = (wid << 3) + (lane >> 3);
  const int scol = ((lane & 7) ^ (lane >> 3)) << 3;

  f32x4 acc[MFR][4] = {};

  auto rdA = [&](int row, int ks) -> bf16x8 {
    return *(const bf16x8*)((const char*)As + row * 128 + ((((ks << 2) | hi) ^ (row & 7)) << 4));
  };
  auto rdB = [&](int row, int ks) -> bf16x8 {
    return *(const bf16x8*)((const char*)Bs + row * 128 + ((((ks << 2) | hi) ^ (row & 7)) << 4));
  };

  for (int k0 = 0; k0 < K; k0 += 64) {
    __syncthreads();
#pragma unroll
    for (int p = 0; p < BM / 32; ++p)
      gload16(A + (row0 + srow + 32 * p) * (size_t)K + k0 + scol, &As[(wid * 8 + 32 * p) * 64]);
#pragma unroll
    for (int p = 0; p < 4; ++p)
      gload16(B + (col0 + srow + 32 * p) * (size_t)K + k0 + scol, &Bs[(wid * 8 + 32 * p) * 64]);
    __syncthreads();
#pragma unroll
    for (int ks = 0; ks < 2; ++ks) {
      bf16x8 af[MFR], bfr[4];
#pragma unroll
      for (int m = 0; m < MFR; ++m) af[m] = rdA(wr + m * 16 + lo, ks);
#pragma unroll
      for (int n = 0; n < 4; ++n) bfr[n] = rdB(wc + n * 16 + lo, ks);
#pragma unroll
      for (int m = 0; m < MFR; ++m)
#pragma unroll
        for (int n = 0; n < 4; ++n)
          acc[m][n] = __builtin_amdgcn_mfma_f32_16x16x32_bf16(af[m], bfr[n], acc[m][n], 0, 0, 0);
    }
  }

#pragma unroll
  for (int m = 0; m < MFR; ++m)
#pragma unroll
    for (int n = 0; n < 4; ++n) {
      const size_t c = col0 + wc + n * 16 + lo;
      const float bv = bias[c];
#pragma unroll
      for (int i = 0; i < 4; ++i) {
        const size_t r = row0 + wr + m * 16 + hi * 4 + i;
        float v = acc[m][n][i] + bv;
        if (RELU) v = fmaxf(v, 0.0f);
        if (WF32) Cf[r * (size_t)N + c] = v;
        if (WB16) Cb[r * (size_t)N + c] = f2b(v);
      }
    }
}

// ---------------- persistent 256x256 8-phase GEMM (FC): 250 blocks x 8 tiles ----------------
template<int KC>
__global__ __launch_bounds__(512, 2)
void gemm256p(const u16* __restrict__ A, const u16* __restrict__ B,
              const float* __restrict__ bias, float* __restrict__ C, int N)
{
  __shared__ __align__(16) u16 LA[2][256 * 64];
  __shared__ __align__(16) u16 LB[2][256 * 64];
  const int tid = threadIdx.x;
  const int wid = tid >> 6, lane = tid & 63;
  const int lo = lane & 15, hi = lane >> 4;
  const int b = blockIdx.x;              // 0..249
  const int bj = b % 125, bi0 = b / 125; // tiles: bi = bi0 + 2j, j=0..7
  const size_t col0 = (size_t)bj << 8;
  const int wrow = (wid >> 2) << 7;
  const int wcol = (wid & 3) << 6;

  const int srow = (wid << 3) + (lane >> 3);
  const int scol = ((lane & 7) ^ (lane >> 3)) << 3;
  const u16* srcB = B + (col0 + srow) * (size_t)KC + scol;
  const int ldst = wid << 9;

  float bv[4];
#pragma unroll
  for (int n = 0; n < 4; ++n) bv[n] = bias[col0 + wcol + n * 16 + lo];
  asm volatile("" : "+v"(bv[0]), "+v"(bv[1]), "+v"(bv[2]), "+v"(bv[3]));

  f32x4 acc[8][4] = {};

  auto stageAB = [&](int s) {
    const int jj = s >> 3, tt = s & 7, buf = s & 1;
    const u16* sA = A + ((size_t)((bi0 + 2 * jj) << 8) + srow) * KC + tt * 64 + scol;
#pragma unroll
    for (int i = 0; i < 4; ++i)
      gload16(sA + (size_t)(i * 64) * KC, &LA[buf][ldst + i * 4096]);
    const u16* sB = srcB + tt * 64;
#pragma unroll
    for (int i = 0; i < 4; ++i)
      gload16(sB + (size_t)(i * 64) * KC, &LB[buf][ldst + i * 4096]);
  };

  auto rd = [&](const u16* base, int row, int ks) -> bf16x8 {
    const int byte = row * 128 + ((((ks << 2) | hi) ^ (row & 7)) << 4);
    return *(const bf16x8*)((const char*)base + byte);
  };

  stageAB(0);
  stageAB(1);

  for (int j = 0; j < 8; ++j) {
#pragma unroll
    for (int t = 0; t < 8; ++t) {
      const int s = j * 8 + t;
      const u16* Ab = LA[s & 1];
      const u16* Bb = LB[s & 1];
      if (j > 0 && t <= 1)  { asm volatile("s_waitcnt vmcnt(40)" ::: "memory"); }
      else if (s == 63)     { asm volatile("s_waitcnt vmcnt(0)" ::: "memory"); }
      else                  { asm volatile("s_waitcnt vmcnt(8)" ::: "memory"); }
      __builtin_amdgcn_sched_barrier(0);
      mbar();

      bf16x8 afr[4], bfr[4];
#pragma unroll
      for (int ks = 0; ks < 2; ++ks) {
#pragma unroll
        for (int m = 0; m < 4; ++m) afr[m] = rd(Ab, wrow + m * 16 + lo, ks);
#pragma unroll
        for (int n = 0; n < 4; ++n) bfr[n] = rd(Bb, wcol + n * 16 + lo, ks);
        mbar();
        asm volatile("s_waitcnt lgkmcnt(0)" ::: "memory");
        __builtin_amdgcn_sched_barrier(0);
        __builtin_amdgcn_s_setprio(1);
#pragma unroll
        for (int m = 0; m < 4; ++m)
#pragma unroll
          for (int n = 0; n < 4; ++n)
            acc[m][n] = __builtin_amdgcn_mfma_f32_16x16x32_bf16(afr[m], bfr[n], acc[m][n], 0, 0, 0);
        __builtin_amdgcn_s_setprio(0);
        mbar();
#pragma unroll
        for (int m = 0; m < 4; ++m) afr[m] = rd(Ab, wrow + (4 + m) * 16 + lo, ks);
        mbar();
        asm volatile("s_waitcnt lgkmcnt(0)" ::: "memory");
        __builtin_amdgcn_sched_barrier(0);
        __builtin_amdgcn_s_setprio(1);
#pragma unroll
        for (int m = 0; m < 4; ++m)
#pragma unroll
          for (int n = 0; n < 4; ++n)
            acc[4 + m][n] = __builtin_amdgcn_mfma_f32_16x16x32_bf16(afr[m], bfr[n], acc[4 + m][n], 0, 0, 0);
        __builtin_amdgcn_s_setprio(0);
        mbar();
      }
      if (s + 2 < 64) stageAB(s + 2);
    }
    const size_t row0 = (size_t)((bi0 + 2 * j) << 8);
#pragma unroll
    for (int m = 0; m < 8; ++m)
#pragma unroll
      for (int n = 0; n < 4; ++n) {
        const size_t c = col0 + wcol + n * 16 + lo;
#pragma unroll
        for (int i = 0; i < 4; ++i) {
          const size_t r = row0 + wrow + m * 16 + hi * 4 + i;
          C[r * (size_t)N + c] = acc[m][n][i] + bv[n];
        }
      }
#pragma unroll
    for (int m = 0; m < 8; ++m)
#pragma unroll
      for (int n = 0; n < 4; ++n)
        acc[m][n] = f32x4{0.f, 0.f, 0.f, 0.f};
  }
}

// ---------------- chunk attention: attend over nc=4 chunks (bf16 qkv) ----------------
__global__ __launch_bounds__(64)
void chunk_attn(const u16* __restrict__ qkv, u16* __restrict__ out) {
  const int p = blockIdx.x, h = blockIdx.y, d = threadIdx.x;
  float q[4], k[4], v[4];
#pragma unroll
  for (int c = 0; c < 4; ++c) {
    const u16* b = qkv + (size_t)((c << 10) + p) * 1536 + (h << 6) + d;
    q[c] = b2f(b[0]); k[c] = b2f(b[512]); v[c] = b2f(b[1024]);
  }
  float sc[4][4];
#pragma unroll
  for (int i = 0; i < 4; ++i)
#pragma unroll
    for (int j = 0; j < 4; ++j) sc[i][j] = q[i] * k[j];
#pragma unroll
  for (int mask = 1; mask < 64; mask <<= 1)
#pragma unroll
    for (int i = 0; i < 4; ++i)
#pragma unroll
      for (int j = 0; j < 4; ++j) sc[i][j] += __shfl_xor(sc[i][j], mask);
#pragma unroll
  for (int i = 0; i < 4; ++i) {
    float s0 = sc[i][0] * 0.125f, s1 = sc[i][1] * 0.125f,
          s2 = sc[i][2] * 0.125f, s3 = sc[i][3] * 0.125f;
    const float mx = fmaxf(fmaxf(s0, s1), fmaxf(s2, s3));
    const float e0 = __expf(s0 - mx), e1 = __expf(s1 - mx),
                e2 = __expf(s2 - mx), e3 = __expf(s3 - mx);
    const float inv = 1.0f / (e0 + e1 + e2 + e3);
    const float o = (e0 * v[0] + e1 * v[1] + e2 * v[2] + e3 * v[3]) * inv;
    out[(size_t)((i << 10) + p) * 512 + (h << 6) + d] = f2b(o);
  }
}

// ---------------- global flash attention: swapped QK^T, in-lane softmax (R4 version) ----------------
__global__ __launch_bounds__(512)
void flash_attn(const u16* __restrict__ qkv, u16* __restrict__ out) {
  __shared__ __align__(16) u16 Ks[64 * 64];
  __shared__ __align__(16) u16 Vt[64 * 64];
  __shared__ __align__(16) u16 Pp[8][16 * 64];
  const int tid = threadIdx.x, wid = tid >> 6, lane = tid & 63;
  const int lo = lane & 15, hi = lane >> 4;
  const int q0 = blockIdx.x << 7, h = blockIdx.y;
  const int hoff = h << 6;
  char* KsB = (char*)Ks; char* VtB = (char*)Vt;
  char* Pw = (char*)&Pp[wid][0];
  const int xsw = (lo & 7) << 4;
  constexpr float C1 = 0.18033688011112042f;   // 0.125 * log2(e)

  bf16x8 qf[2];
#pragma unroll
  for (int kh = 0; kh < 2; ++kh)
    qf[kh] = *(const bf16x8*)(qkv + (size_t)(q0 + wid * 16 + lo) * 1536 + hoff + kh * 32 + hi * 8);

  f32x4 o[4] = {};
  float mr = -3e38f, lr = 0.f;

  const int krow = tid >> 3, kq = tid & 7;

  bf16x8 kpre = *(const bf16x8*)(qkv + (size_t)krow * 1536 + 512 + hoff + kq * 8);
  bf16x8 vpre = *(const bf16x8*)(qkv + (size_t)krow * 1536 + 1024 + hoff + kq * 8);

  for (int kv0 = 0; kv0 < 4096; kv0 += 64) {
    __syncthreads();
    *(bf16x8*)(KsB + ((krow * 128 + kq * 16) ^ ((krow & 7) << 4))) = kpre;
    {
      const unsigned* vp = (const unsigned*)&vpre;
      const int oddr = krow & 1;
      const unsigned t0 = oddr ? vp[0] : vp[2];
      const unsigned t1 = oddr ? vp[1] : vp[3];
      const unsigned r0 = (unsigned)__shfl_xor((int)t0, 8);
      const unsigned r1 = (unsigned)__shfl_xor((int)t1, 8);
      const unsigned E0 = oddr ? r0 : vp[0];
      const unsigned E1 = oddr ? r1 : vp[1];
      const unsigned O0 = oddr ? vp[2] : r0;
      const unsigned O1 = oddr ? vp[3] : r1;
      const int jp = krow & ~1;
      const int db = kq * 8 + oddr * 4;
      unsigned w0 = (E0 & 0xffffu) | (O0 << 16);
      unsigned w1 = (E0 >> 16) | (O0 & 0xffff0000u);
      unsigned w2 = (E1 & 0xffffu) | (O1 << 16);
      unsigned w3 = (E1 >> 16) | (O1 & 0xffff0000u);
      *(unsigned*)(VtB + (((db + 0) * 128 + 2 * jp) ^ (((db + 0) & 7) << 4))) = w0;
      *(unsigned*)(VtB + (((db + 1) * 128 + 2 * jp) ^ (((db + 1) & 7) << 4))) = w1;
      *(unsigned*)(VtB + (((db + 2) * 128 + 2 * jp) ^ (((db + 2) & 7) << 4))) = w2;
      *(unsigned*)(VtB + (((db + 3) * 128 + 2 * jp) ^ (((db + 3) & 7) << 4))) = w3;
    }
    __syncthreads();
    if (kv0 + 64 < 4096) {
      kpre = *(const bf16x8*)(qkv + (size_t)(kv0 + 64 + krow) * 1536 + 512 + hoff + kq * 8);
      vpre = *(const bf16x8*)(qkv + (size_t)(kv0 + 64 + krow) * 1536 + 1024 + hoff + kq * 8);
    }

    f32x4 s[4] = {};
#pragma unroll
    for (int n = 0; n < 4; ++n) {
      const int key = n * 16 + lo;
#pragma unroll
      for (int kh = 0; kh < 2; ++kh) {
        bf16x8 kf = *(const bf16x8*)(KsB + ((key * 128 + kh * 64 + hi * 16) ^ ((key & 7) << 4)));
        s[n] = __builtin_amdgcn_mfma_f32_16x16x32_bf16(kf, qf[kh], s[n], 0, 0, 0);
      }
    }

    float pmx = s[0][0];
#pragma unroll
    for (int n = 0; n < 4; ++n)
#pragma unroll
      for (int i = 0; i < 4; ++i) pmx = fmaxf(pmx, s[n][i]);
    pmx = fmaxf(pmx, __shfl_xor(pmx, 16));
    pmx = fmaxf(pmx, __shfl_xor(pmx, 32));

    if (__any(pmx > mr + 64.f)) {
      const float mn = fmaxf(mr, pmx);
      const float sc = exp2f((mr - mn) * C1);
      mr = mn;
      lr *= sc;
#pragma unroll
      for (int i = 0; i < 4; ++i) {
        const float sq = __shfl(sc, hi * 4 + i);
#pragma unroll
        for (int n = 0; n < 4; ++n) o[n][i] *= sq;
      }
    }

    const float mc = mr * C1;
    float rs = 0.f;
    unsigned U[8];
#pragma unroll
    for (int n = 0; n < 4; ++n) {
      const float p0 = exp2f(fmaf(s[n][0], C1, -mc));
      const float p1 = exp2f(fmaf(s[n][1], C1, -mc));
      const float p2 = exp2f(fmaf(s[n][2], C1, -mc));
      const float p3 = exp2f(fmaf(s[n][3], C1, -mc));
      rs += (p0 + p1) + (p2 + p3);
      asm("v_cvt_pk_bf16_f32 %0, %1, %2" : "=v"(U[2 * n])     : "v"(p0), "v"(p1));
      asm("v_cvt_pk_bf16_f32 %0, %1, %2" : "=v"(U[2 * n + 1]) : "v"(p2), "v"(p3));
    }
    rs += __shfl_xor(rs, 16);
    rs += __shfl_xor(rs, 32);
    lr += rs;
#pragma unroll
    for (int n = 0; n < 4; ++n) {
      const int off = lo * 128 + ((n * 32 + hi * 8) ^ xsw);
      const unsigned long long dw = (unsigned long long)U[2 * n] |
                                    ((unsigned long long)U[2 * n + 1] << 32);
      *(unsigned long long*)(Pw + off) = dw;
    }

#pragma unroll
    for (int kh = 0; kh < 2; ++kh) {
      bf16x8 pa = *(const bf16x8*)(Pw + lo * 128 + ((kh * 64 + hi * 16) ^ xsw));
#pragma unroll
      for (int n = 0; n < 4; ++n) {
        const int vd = n * 16 + lo;
        bf16x8 vf = *(const bf16x8*)(VtB + ((vd * 128 + kh * 64 + hi * 16) ^ ((vd & 7) << 4)));
        o[n] = __builtin_amdgcn_mfma_f32_16x16x32_bf16(pa, vf, o[n], 0, 0, 0);
      }
    }
  }

#pragma unroll
  for (int i = 0; i < 4; ++i) {
    const float lq = __shfl(lr, hi * 4 + i);
    const float inv = 1.0f / lq;
    const int r = q0 + wid * 16 + hi * 4 + i;
#pragma unroll
    for (int n = 0; n < 4; ++n)
      out[(size_t)r * 512 + hoff + n * 16 + lo] = f2b(o[n][i] * inv);
  }
}

// ---------------- residual add + LayerNorm ----------------
__global__ __launch_bounds__(256)
void add_ln(const float* __restrict__ a, const float* __restrict__ b,
            const float* __restrict__ g, const float* __restrict__ be,
            float* __restrict__ of, u16* __restrict__ ob) {
  const int wid = threadIdx.x >> 6, lane = threadIdx.x & 63;
  const int row = blockIdx.x * 4 + wid;
  const size_t base = (size_t)row * 512 + lane * 8;
  float4 a0 = *(const float4*)(a + base), a1 = *(const float4*)(a + base + 4);
  float4 b0 = *(const float4*)(b + base), b1 = *(const float4*)(b + base + 4);
  float x[8] = {a0.x + b0.x, a0.y + b0.y, a0.z + b0.z, a0.w + b0.w,
                a1.x + b1.x, a1.y + b1.y, a1.z + b1.z, a1.w + b1.w};
  float s = 0.f, sq = 0.f;
#pragma unroll
  for (int j = 0; j < 8; ++j) { s += x[j]; sq += x[j] * x[j]; }
#pragma unroll
  for (int mask = 1; mask < 64; mask <<= 1) {
    s += __shfl_xor(s, mask);
    sq += __shfl_xor(sq, mask);
  }
  const float mean = s * (1.0f / 512.0f);
  const float var = sq * (1.0f / 512.0f) - mean * mean;
  const float rstd = rsqrtf(var + 1e-5f);
  float4 g0 = *(const float4*)(g + lane * 8), g1 = *(const float4*)(g + lane * 8 + 4);
  float4 e0 = *(const float4*)(be + lane * 8), e1 = *(const float4*)(be + lane * 8 + 4);
  const float gg[8] = {g0.x, g0.y, g0.z, g0.w, g1.x, g1.y, g1.z, g1.w};
  const float bb[8] = {e0.x, e0.y, e0.z, e0.w, e1.x, e1.y, e1.z, e1.w};
#pragma unroll
  for (int j = 0; j < 8; ++j) {
    const float y = (x[j] - mean) * rstd * gg[j] + bb[j];
    of[base + j] = y;
    ob[base + j] = f2b(y);
  }
}

extern "C" void kernel_launch(void* const* d_in, const int* in_sizes, int n_in,
                              void* d_out, int out_size, void* d_ws, size_t ws_size,
                              hipStream_t stream) {
  (void)in_sizes; (void)n_in; (void)out_size; (void)ws_size;
  const int*   tokens = (const int*)d_in[0];
  const float* emb    = (const float*)d_in[1];
  const float* cwin   = (const float*)d_in[2];
  const float* cbin   = (const float*)d_in[3];
  const float* cwout  = (const float*)d_in[4];
  const float* cbout  = (const float*)d_in[5];
  const float* gwin   = (const float*)d_in[6];
  const float* gbin   = (const float*)d_in[7];
  const float* gwout  = (const float*)d_in[8];
  const float* gbout  = (const float*)d_in[9];
  const float* ln1g   = (const float*)d_in[10];
  const float* ln1b   = (const float*)d_in[11];
  const float* fw1    = (const float*)d_in[12];
  const float* fb1    = (const float*)d_in[13];
  const float* fw2    = (const float*)d_in[14];
  const float* fb2    = (const float*)d_in[15];
  const float* ln2g   = (const float*)d_in[16];
  const float* ln2b   = (const float*)d_in[17];
  const float* fcw    = (const float*)d_in[18];
  const float* fcb    = (const float*)d_in[19];
  float* out = (float*)d_out;

  char* ws = (char*)d_ws;
  size_t off = 0;
  auto alloc = [&](size_t bytes) -> void* {
    void* p = ws + off;
    off += (bytes + 255) & ~(size_t)255;
    return p;
  };
  u16*   xb    = (u16*)alloc((size_t)4096 * 512 * 2);
  float* xf    = (float*)alloc((size_t)4096 * 512 * 4);
  u16*   qkv1b = (u16*)alloc((size_t)4096 * 1536 * 2);
  u16*   at1   = (u16*)alloc((size_t)4096 * 512 * 2);
  u16*   cab   = (u16*)alloc((size_t)4096 * 512 * 2);
  u16*   qkv2  = (u16*)alloc((size_t)4096 * 1536 * 2);
  u16*   at2   = (u16*)alloc((size_t)4096 * 512 * 2);
  float* gaf   = (float*)alloc((size_t)4096 * 512 * 4);
  float* x1f   = (float*)alloc((size_t)4096 * 512 * 4);
  u16*   x1b   = (u16*)alloc((size_t)4096 * 512 * 2);
  u16*   f1b   = (u16*)alloc((size_t)4096 * 2048 * 2);
  float* ff    = (float*)alloc((size_t)4096 * 512 * 4);
  float* x2f   = (float*)alloc((size_t)4096 * 512 * 4);
  u16*   x2b   = (u16*)alloc((size_t)4096 * 512 * 2);
  u16*   wcinb  = (u16*)alloc((size_t)1536 * 512 * 2);
  u16*   wcoutb = (u16*)alloc((size_t)512 * 512 * 2);
  u16*   wginb  = (u16*)alloc((size_t)1536 * 512 * 2);
  u16*   wgoutb = (u16*)alloc((size_t)512 * 512 * 2);
  u16*   wf1b   = (u16*)alloc((size_t)2048 * 512 * 2);
  u16*   wf2b   = (u16*)alloc((size_t)512 * 2048 * 2);
  u16*   wfcb   = (u16*)alloc((size_t)32000 * 512 * 2);

  f2b_multi<<<2048, 256, 0, stream>>>(
      (const float4*)cwin, wcinb, (const float4*)cwout, wcoutb,
      (const float4*)gwin, wginb, (const float4*)gwout, wgoutb,
      (const float4*)fw1, wf1b, (const float4*)fw2, wf2b,
      (const float4*)fcw, wfcb);

  embed_pe<<<4096, 256, 0, stream>>>(tokens, emb, xf, xb);

  // chunk stage
  gemm_bt<128, 0, 0, 1><<<384, 256, 0, stream>>>(xb, wcinb, cbin, (float*)nullptr, qkv1b, 4096, 1536, 512);
  chunk_attn<<<dim3(1024, 8), 64, 0, stream>>>(qkv1b, at1);
  gemm_bt<64, 0, 0, 1><<<256, 256, 0, stream>>>(at1, wcoutb, cbout, (float*)nullptr, cab, 4096, 512, 512);

  // global stage
  gemm_bt<128, 0, 0, 1><<<384, 256, 0, stream>>>(cab, wginb, gbin, (float*)nullptr, qkv2, 4096, 1536, 512);
  flash_attn<<<dim3(32, 8), 512, 0, stream>>>(qkv2, at2);
  gemm_bt<64, 0, 1, 0><<<256, 256, 0, stream>>>(at2, wgoutb, gbout, gaf, (u16*)nullptr, 4096, 512, 512);

  // post-norm encoder layer
  add_ln<<<1024, 256, 0, stream>>>(xf, gaf, ln1g, ln1b, x1f, x1b);
  gemm_bt<128, 1, 0, 1><<<512, 256, 0, stream>>>(x1b, wf1b, fb1, (float*)nullptr, f1b, 4096, 2048, 512);
  gemm_bt<64, 0, 1, 0><<<256, 256, 0, stream>>>(f1b, wf2b, fb2, ff, (u16*)nullptr, 4096, 512, 2048);
  add_ln<<<1024, 256, 0, stream>>>(x1f, ff, ln2g, ln2b, x2f, x2b);

  // vocab projection: persistent 256^2 pipeline, 250 blocks x 8 tiles
  gemm256p<512><<<250, 512, 0, stream>>>(x2b, wfcb, fcb, out, 32000);
}

// Round 7
// 453.609 us; speedup vs baseline: 1.1085x; 1.1085x over previous
//
#include <hip/hip_runtime.h>

typedef __attribute__((ext_vector_type(8))) short bf16x8;
typedef __attribute__((ext_vector_type(4))) float f32x4;
typedef unsigned short u16;

__device__ __forceinline__ u16 f2b(float f) {
  union { float f; unsigned u; } v; v.f = f;
  return (u16)((v.u + 0x7FFFu + ((v.u >> 16) & 1u)) >> 16);
}
__device__ __forceinline__ float b2f(u16 x) {
  union { unsigned u; float f; } v; v.u = (unsigned)x << 16; return v.f;
}

__device__ __forceinline__ void gload16(const void* g, void* l) {
  __builtin_amdgcn_global_load_lds((__attribute__((address_space(1))) void*)(g),
                                   (__attribute__((address_space(3))) void*)(l),
                                   16, 0, 0);
}

__device__ __forceinline__ void mbar() {
  asm volatile("" ::: "memory");
  __builtin_amdgcn_s_barrier();
  asm volatile("" ::: "memory");
}

// ---------------- batched fp32 -> bf16 (all 7 weight tensors, one launch) ----------------
__device__ __forceinline__ void cv1(const float4* __restrict__ s, u16* __restrict__ d, int i) {
  float4 v = s[i];
  unsigned long long pk = (unsigned long long)f2b(v.x) |
                          ((unsigned long long)f2b(v.y) << 16) |
                          ((unsigned long long)f2b(v.z) << 32) |
                          ((unsigned long long)f2b(v.w) << 48);
  *(unsigned long long*)(d + (size_t)i * 4) = pk;
}

__global__ __launch_bounds__(256)
void f2b_multi(const float4* s0, u16* d0, const float4* s1, u16* d1,
               const float4* s2, u16* d2, const float4* s3, u16* d3,
               const float4* s4, u16* d4, const float4* s5, u16* d5,
               const float4* s6, u16* d6) {
  int i = blockIdx.x * 256 + threadIdx.x;
  const int stride = gridDim.x * 256;
  for (; i < 5144576; i += stride) {
    int j = i;
    if (j < 196608) { cv1(s0, d0, j); continue; }
    j -= 196608;
    if (j < 65536) { cv1(s1, d1, j); continue; }
    j -= 65536;
    if (j < 196608) { cv1(s2, d2, j); continue; }
    j -= 196608;
    if (j < 65536) { cv1(s3, d3, j); continue; }
    j -= 65536;
    if (j < 262144) { cv1(s4, d4, j); continue; }
    j -= 262144;
    if (j < 262144) { cv1(s5, d5, j); continue; }
    j -= 262144;
    cv1(s6, d6, j);
  }
}

// ---------------- embedding * sqrt(D) + sinusoidal PE ----------------
__global__ __launch_bounds__(256) void embed_pe(const int* __restrict__ tok,
    const float* __restrict__ emb, float* __restrict__ xf, u16* __restrict__ xb) {
  const int s = blockIdx.x;
  const int i = threadIdx.x;
  const int t = tok[s];
  const float div = __expf((float)(2 * i) * -0.017988946039015984f);
  const float ang = (float)s * div;
  const float sv = __sinf(ang), cv = __cosf(ang);
  const float* e = emb + (size_t)t * 512 + 2 * i;
  const float x0 = e[0] * 22.627416997969522f + sv;
  const float x1 = e[1] * 22.627416997969522f + cv;
  const size_t o = (size_t)s * 512 + 2 * i;
  xf[o] = x0; xf[o + 1] = x1;
  xb[o] = f2b(x0); xb[o + 1] = f2b(x1);
}

// ---------------- tiled GEMM: C = A(MxK) . B(NxK)^T + bias; BK=64, swizzled LDS ----------------
template<int BM, int RELU, int WF32, int WB16>
__global__ __launch_bounds__(256)
void gemm_bt(const u16* __restrict__ A, const u16* __restrict__ B,
             const float* __restrict__ bias, float* __restrict__ Cf,
             u16* __restrict__ Cb, int M, int N, int K)
{
  constexpr int MFR = BM / 32;
  __shared__ __align__(16) u16 As[BM * 64];
  __shared__ __align__(16) u16 Bs[128 * 64];
  const int tid = threadIdx.x;
  const int wid = tid >> 6, lane = tid & 63;
  const int lo = lane & 15, hi = lane >> 4;
  const int nbn = N >> 7;
  const int cpx = (int)gridDim.x >> 3;
  const int bid = blockIdx.x;
  const int swz = (bid & 7) * cpx + (bid >> 3);
  const int bi = swz / nbn, bj = swz - bi * nbn;
  const size_t row0 = (size_t)bi * BM, col0 = (size_t)bj << 7;
  const int wr = (wid >> 1) * (BM / 2), wc = (wid & 1) << 6;
  const int srow = (wid << 3) + (lane >> 3);
  const int scol = ((lane & 7) ^ (lane >> 3)) << 3;

  f32x4 acc[MFR][4] = {};

  auto rdA = [&](int row, int ks) -> bf16x8 {
    return *(const bf16x8*)((const char*)As + row * 128 + ((((ks << 2) | hi) ^ (row & 7)) << 4));
  };
  auto rdB = [&](int row, int ks) -> bf16x8 {
    return *(const bf16x8*)((const char*)Bs + row * 128 + ((((ks << 2) | hi) ^ (row & 7)) << 4));
  };

  for (int k0 = 0; k0 < K; k0 += 64) {
    __syncthreads();
#pragma unroll
    for (int p = 0; p < BM / 32; ++p)
      gload16(A + (row0 + srow + 32 * p) * (size_t)K + k0 + scol, &As[(wid * 8 + 32 * p) * 64]);
#pragma unroll
    for (int p = 0; p < 4; ++p)
      gload16(B + (col0 + srow + 32 * p) * (size_t)K + k0 + scol, &Bs[(wid * 8 + 32 * p) * 64]);
    __syncthreads();
#pragma unroll
    for (int ks = 0; ks < 2; ++ks) {
      bf16x8 af[MFR], bfr[4];
#pragma unroll
      for (int m = 0; m < MFR; ++m) af[m] = rdA(wr + m * 16 + lo, ks);
#pragma unroll
      for (int n = 0; n < 4; ++n) bfr[n] = rdB(wc + n * 16 + lo, ks);
#pragma unroll
      for (int m = 0; m < MFR; ++m)
#pragma unroll
        for (int n = 0; n < 4; ++n)
          acc[m][n] = __builtin_amdgcn_mfma_f32_16x16x32_bf16(af[m], bfr[n], acc[m][n], 0, 0, 0);
    }
  }

#pragma unroll
  for (int m = 0; m < MFR; ++m)
#pragma unroll
    for (int n = 0; n < 4; ++n) {
      const size_t c = col0 + wc + n * 16 + lo;
      const float bv = bias[c];
#pragma unroll
      for (int i = 0; i < 4; ++i) {
        const size_t r = row0 + wr + m * 16 + hi * 4 + i;
        float v = acc[m][n][i] + bv;
        if (RELU) v = fmaxf(v, 0.0f);
        if (WF32) Cf[r * (size_t)N + c] = v;
        if (WB16) Cb[r * (size_t)N + c] = f2b(v);
      }
    }
}

// ---------------- 256x256 8-phase GEMM (FC projection), 2000 blocks, nt stores ----------------
template<int KC>
__global__ __launch_bounds__(512, 2)
void gemm256(const u16* __restrict__ A, const u16* __restrict__ B,
             const float* __restrict__ bias, float* __restrict__ C,
             int M, int N)
{
  constexpr int T = KC / 64;
  __shared__ __align__(16) u16 LA[2][256 * 64];
  __shared__ __align__(16) u16 LB[2][256 * 64];
  const int tid = threadIdx.x;
  const int wid = tid >> 6, lane = tid & 63;
  const int lo = lane & 15, hi = lane >> 4;
  const int nbn = N >> 8;
  const int cpx = (int)gridDim.x >> 3;
  const int bid = blockIdx.x;
  const int swz = (bid & 7) * cpx + (bid >> 3);
  const int bi = swz / nbn, bj = swz - bi * nbn;
  const size_t row0 = (size_t)bi << 8, col0 = (size_t)bj << 8;
  const int wrow = (wid >> 2) << 7;
  const int wcol = (wid & 3) << 6;

  const int srow = (wid << 3) + (lane >> 3);
  const int scol = ((lane & 7) ^ (lane >> 3)) << 3;
  const u16* srcA = A + (row0 + srow) * (size_t)KC + scol;
  const u16* srcB = B + (col0 + srow) * (size_t)KC + scol;
  const int ldst = wid << 9;

  f32x4 acc[8][4] = {};

  auto stage = [&](int t, int b) {
    const size_t ko = (size_t)t * 64;
#pragma unroll
    for (int i = 0; i < 4; ++i)
      gload16(srcA + ko + (size_t)(i * 64) * KC, &LA[b][ldst + i * 4096]);
#pragma unroll
    for (int i = 0; i < 4; ++i)
      gload16(srcB + ko + (size_t)(i * 64) * KC, &LB[b][ldst + i * 4096]);
  };

  auto rd = [&](const u16* base, int row, int ks) -> bf16x8 {
    const int byte = row * 128 + ((((ks << 2) | hi) ^ (row & 7)) << 4);
    return *(const bf16x8*)((const char*)base + byte);
  };

  stage(0, 0);
  stage(1, 1);

  for (int t = 0; t < T; ++t) {
    const int b = t & 1;
    const u16* Ab = LA[b];
    const u16* Bb = LB[b];
    if (t + 1 < T) { asm volatile("s_waitcnt vmcnt(8)" ::: "memory"); }
    else           { asm volatile("s_waitcnt vmcnt(0)" ::: "memory"); }
    __builtin_amdgcn_sched_barrier(0);
    mbar();

    bf16x8 afr[4], bfr[4];
#pragma unroll
    for (int ks = 0; ks < 2; ++ks) {
#pragma unroll
      for (int m = 0; m < 4; ++m) afr[m] = rd(Ab, wrow + m * 16 + lo, ks);
#pragma unroll
      for (int n = 0; n < 4; ++n) bfr[n] = rd(Bb, wcol + n * 16 + lo, ks);
      mbar();
      asm volatile("s_waitcnt lgkmcnt(0)" ::: "memory");
      __builtin_amdgcn_sched_barrier(0);
      __builtin_amdgcn_s_setprio(1);
#pragma unroll
      for (int m = 0; m < 4; ++m)
#pragma unroll
        for (int n = 0; n < 4; ++n)
          acc[m][n] = __builtin_amdgcn_mfma_f32_16x16x32_bf16(afr[m], bfr[n], acc[m][n], 0, 0, 0);
      __builtin_amdgcn_s_setprio(0);
      mbar();
#pragma unroll
      for (int m = 0; m < 4; ++m) afr[m] = rd(Ab, wrow + (4 + m) * 16 + lo, ks);
      mbar();
      asm volatile("s_waitcnt lgkmcnt(0)" ::: "memory");
      __builtin_amdgcn_sched_barrier(0);
      __builtin_amdgcn_s_setprio(1);
#pragma unroll
      for (int m = 0; m < 4; ++m)
#pragma unroll
        for (int n = 0; n < 4; ++n)
          acc[4 + m][n] = __builtin_amdgcn_mfma_f32_16x16x32_bf16(afr[m], bfr[n], acc[4 + m][n], 0, 0, 0);
      __builtin_amdgcn_s_setprio(0);
      mbar();
    }
    if (t + 2 < T) stage(t + 2, b);   // must stay post-compute: writes buffer b (tile t's)
  }

  // epilogue: nontemporal streaming stores (output never re-read)
#pragma unroll
  for (int m = 0; m < 8; ++m)
#pragma unroll
    for (int n = 0; n < 4; ++n) {
      const size_t c = col0 + wcol + n * 16 + lo;
      const float bv = bias[c];
#pragma unroll
      for (int i = 0; i < 4; ++i) {
        const size_t r = row0 + wrow + m * 16 + hi * 4 + i;
        __builtin_nontemporal_store(acc[m][n][i] + bv, &C[r * (size_t)N + c]);
      }
    }
}

// ---------------- chunk attention: attend over nc=4 chunks (bf16 qkv) ----------------
__global__ __launch_bounds__(64)
void chunk_attn(const u16* __restrict__ qkv, u16* __restrict__ out) {
  const int p = blockIdx.x, h = blockIdx.y, d = threadIdx.x;
  float q[4], k[4], v[4];
#pragma unroll
  for (int c = 0; c < 4; ++c) {
    const u16* b = qkv + (size_t)((c << 10) + p) * 1536 + (h << 6) + d;
    q[c] = b2f(b[0]); k[c] = b2f(b[512]); v[c] = b2f(b[1024]);
  }
  float sc[4][4];
#pragma unroll
  for (int i = 0; i < 4; ++i)
#pragma unroll
    for (int j = 0; j < 4; ++j) sc[i][j] = q[i] * k[j];
#pragma unroll
  for (int mask = 1; mask < 64; mask <<= 1)
#pragma unroll
    for (int i = 0; i < 4; ++i)
#pragma unroll
      for (int j = 0; j < 4; ++j) sc[i][j] += __shfl_xor(sc[i][j], mask);
#pragma unroll
  for (int i = 0; i < 4; ++i) {
    float s0 = sc[i][0] * 0.125f, s1 = sc[i][1] * 0.125f,
          s2 = sc[i][2] * 0.125f, s3 = sc[i][3] * 0.125f;
    const float mx = fmaxf(fmaxf(s0, s1), fmaxf(s2, s3));
    const float e0 = __expf(s0 - mx), e1 = __expf(s1 - mx),
                e2 = __expf(s2 - mx), e3 = __expf(s3 - mx);
    const float inv = 1.0f / (e0 + e1 + e2 + e3);
    const float o = (e0 * v[0] + e1 * v[1] + e2 * v[2] + e3 * v[3]) * inv;
    out[(size_t)((i << 10) + p) * 512 + (h << 6) + d] = f2b(o);
  }
}

// ---------------- global flash attention: KV-split x2, swapped QK^T ----------------
__global__ __launch_bounds__(512, 4)
void flash_attn(const u16* __restrict__ qkv, float* __restrict__ pO,
                float* __restrict__ pm, float* __restrict__ pl) {
  __shared__ __align__(16) u16 Ks[64 * 64];
  __shared__ __align__(16) u16 Vt[64 * 64];
  __shared__ __align__(16) u16 Pp[8][16 * 64];
  const int tid = threadIdx.x, wid = tid >> 6, lane = tid & 63;
  const int lo = lane & 15, hi = lane >> 4;
  const int q0 = blockIdx.x << 7, h = blockIdx.y, z = blockIdx.z;
  const int kvb = z << 11;
  const int hoff = h << 6;
  char* KsB = (char*)Ks; char* VtB = (char*)Vt;
  char* Pw = (char*)&Pp[wid][0];
  const int xsw = (lo & 7) << 4;
  constexpr float C1 = 0.18033688011112042f;

  bf16x8 qf[2];
#pragma unroll
  for (int kh = 0; kh < 2; ++kh)
    qf[kh] = *(const bf16x8*)(qkv + (size_t)(q0 + wid * 16 + lo) * 1536 + hoff + kh * 32 + hi * 8);

  f32x4 o[4] = {};
  float mr = -3e38f, lr = 0.f;

  const int krow = tid >> 3, kq = tid & 7;

  bf16x8 kpre = *(const bf16x8*)(qkv + (size_t)(kvb + krow) * 1536 + 512 + hoff + kq * 8);
  bf16x8 vpre = *(const bf16x8*)(qkv + (size_t)(kvb + krow) * 1536 + 1024 + hoff + kq * 8);

  for (int kv0 = kvb; kv0 < kvb + 2048; kv0 += 64) {
    __syncthreads();
    *(bf16x8*)(KsB + ((krow * 128 + kq * 16) ^ ((krow & 7) << 4))) = kpre;
    {
      const unsigned* vp = (const unsigned*)&vpre;
      const int oddr = krow & 1;
      const unsigned t0 = oddr ? vp[0] : vp[2];
      const unsigned t1 = oddr ? vp[1] : vp[3];
      const unsigned r0 = (unsigned)__shfl_xor((int)t0, 8);
      const unsigned r1 = (unsigned)__shfl_xor((int)t1, 8);
      const unsigned E0 = oddr ? r0 : vp[0];
      const unsigned E1 = oddr ? r1 : vp[1];
      const unsigned O0 = oddr ? vp[2] : r0;
      const unsigned O1 = oddr ? vp[3] : r1;
      const int jp = krow & ~1;
      const int db = kq * 8 + oddr * 4;
      unsigned w0 = (E0 & 0xffffu) | (O0 << 16);
      unsigned w1 = (E0 >> 16) | (O0 & 0xffff0000u);
      unsigned w2 = (E1 & 0xffffu) | (O1 << 16);
      unsigned w3 = (E1 >> 16) | (O1 & 0xffff0000u);
      *(unsigned*)(VtB + (((db + 0) * 128 + 2 * jp) ^ (((db + 0) & 7) << 4))) = w0;
      *(unsigned*)(VtB + (((db + 1) * 128 + 2 * jp) ^ (((db + 1) & 7) << 4))) = w1;
      *(unsigned*)(VtB + (((db + 2) * 128 + 2 * jp) ^ (((db + 2) & 7) << 4))) = w2;
      *(unsigned*)(VtB + (((db + 3) * 128 + 2 * jp) ^ (((db + 3) & 7) << 4))) = w3;
    }
    __syncthreads();
    if (kv0 + 64 < kvb + 2048) {
      kpre = *(const bf16x8*)(qkv + (size_t)(kv0 + 64 + krow) * 1536 + 512 + hoff + kq * 8);
      vpre = *(const bf16x8*)(qkv + (size_t)(kv0 + 64 + krow) * 1536 + 1024 + hoff + kq * 8);
    }

    f32x4 s[4] = {};
#pragma unroll
    for (int n = 0; n < 4; ++n) {
      const int key = n * 16 + lo;
#pragma unroll
      for (int kh = 0; kh < 2; ++kh) {
        bf16x8 kf = *(const bf16x8*)(KsB + ((key * 128 + kh * 64 + hi * 16) ^ ((key & 7) << 4)));
        s[n] = __builtin_amdgcn_mfma_f32_16x16x32_bf16(kf, qf[kh], s[n], 0, 0, 0);
      }
    }

    float pmx = s[0][0];
#pragma unroll
    for (int n = 0; n < 4; ++n)
#pragma unroll
      for (int i = 0; i < 4; ++i) pmx = fmaxf(pmx, s[n][i]);
    pmx = fmaxf(pmx, __shfl_xor(pmx, 16));
    pmx = fmaxf(pmx, __shfl_xor(pmx, 32));

    if (__any(pmx > mr + 64.f)) {
      const float mn = fmaxf(mr, pmx);
      const float sc = exp2f((mr - mn) * C1);
      mr = mn;
      lr *= sc;
#pragma unroll
      for (int i = 0; i < 4; ++i) {
        const float sq = __shfl(sc, hi * 4 + i);
#pragma unroll
        for (int n = 0; n < 4; ++n) o[n][i] *= sq;
      }
    }

    const float mc = mr * C1;
    float rs = 0.f;
    unsigned U[8];
#pragma unroll
    for (int n = 0; n < 4; ++n) {
      const float p0 = exp2f(fmaf(s[n][0], C1, -mc));
      const float p1 = exp2f(fmaf(s[n][1], C1, -mc));
      const float p2 = exp2f(fmaf(s[n][2], C1, -mc));
      const float p3 = exp2f(fmaf(s[n][3], C1, -mc));
      rs += (p0 + p1) + (p2 + p3);
      asm("v_cvt_pk_bf16_f32 %0, %1, %2" : "=v"(U[2 * n])     : "v"(p0), "v"(p1));
      asm("v_cvt_pk_bf16_f32 %0, %1, %2" : "=v"(U[2 * n + 1]) : "v"(p2), "v"(p3));
    }
    rs += __shfl_xor(rs, 16);
    rs += __shfl_xor(rs, 32);
    lr += rs;
#pragma unroll
    for (int n = 0; n < 4; ++n) {
      const int off = lo * 128 + ((n * 32 + hi * 8) ^ xsw);
      const unsigned long long dw = (unsigned long long)U[2 * n] |
                                    ((unsigned long long)U[2 * n + 1] << 32);
      *(unsigned long long*)(Pw + off) = dw;
    }

#pragma unroll
    for (int kh = 0; kh < 2; ++kh) {
      bf16x8 pa = *(const bf16x8*)(Pw + lo * 128 + ((kh * 64 + hi * 16) ^ xsw));
#pragma unroll
      for (int n = 0; n < 4; ++n) {
        const int vd = n * 16 + lo;
        bf16x8 vf = *(const bf16x8*)(VtB + ((vd * 128 + kh * 64 + hi * 16) ^ ((vd & 7) << 4)));
        o[n] = __builtin_amdgcn_mfma_f32_16x16x32_bf16(pa, vf, o[n], 0, 0, 0);
      }
    }
  }

#pragma unroll
  for (int i = 0; i < 4; ++i) {
    const int r = q0 + wid * 16 + hi * 4 + i;
#pragma unroll
    for (int n = 0; n < 4; ++n)
      pO[((size_t)z * 4096 + r) * 512 + hoff + n * 16 + lo] = o[n][i];
  }
  if (hi == 0) {
    const int r = q0 + wid * 16 + lo;
    pm[(z * 8 + h) * 4096 + r] = mr;
    pl[(z * 8 + h) * 4096 + r] = lr;
  }
}

// ---------------- merge the two KV-half partials ----------------
__global__ __launch_bounds__(256)
void attn_merge(const float* __restrict__ pO, const float* __restrict__ pm,
                const float* __restrict__ pl, u16* __restrict__ out) {
  constexpr float C1 = 0.18033688011112042f;
  const int tid = threadIdx.x, lane = tid & 63, w = tid >> 6;
  const int row = blockIdx.x * 4 + w;
  const int d = lane * 8, h = lane >> 3;
  const float m0 = pm[h * 4096 + row], m1 = pm[(8 + h) * 4096 + row];
  const float l0 = pl[h * 4096 + row], l1 = pl[(8 + h) * 4096 + row];
  const float M = fmaxf(m0, m1);
  const float w0 = exp2f((m0 - M) * C1), w1 = exp2f((m1 - M) * C1);
  const float inv = 1.0f / (l0 * w0 + l1 * w1);
  const float* a = pO + (size_t)row * 512 + d;
  const float* b = pO + ((size_t)4096 + row) * 512 + d;
  float4 a0 = *(const float4*)a, a1 = *(const float4*)(a + 4);
  float4 b0 = *(const float4*)b, b1 = *(const float4*)(b + 4);
  const float A[8] = {a0.x, a0.y, a0.z, a0.w, a1.x, a1.y, a1.z, a1.w};
  const float Bv[8] = {b0.x, b0.y, b0.z, b0.w, b1.x, b1.y, b1.z, b1.w};
#pragma unroll
  for (int j = 0; j < 8; ++j)
    out[(size_t)row * 512 + d + j] = f2b((A[j] * w0 + Bv[j] * w1) * inv);
}

// ---------------- residual add + LayerNorm ----------------
__global__ __launch_bounds__(256)
void add_ln(const float* __restrict__ a, const float* __restrict__ b,
            const float* __restrict__ g, const float* __restrict__ be,
            float* __restrict__ of, u16* __restrict__ ob) {
  const int wid = threadIdx.x >> 6, lane = threadIdx.x & 63;
  const int row = blockIdx.x * 4 + wid;
  const size_t base = (size_t)row * 512 + lane * 8;
  float4 a0 = *(const float4*)(a + base), a1 = *(const float4*)(a + base + 4);
  float4 b0 = *(const float4*)(b + base), b1 = *(const float4*)(b + base + 4);
  float x[8] = {a0.x + b0.x, a0.y + b0.y, a0.z + b0.z, a0.w + b0.w,
                a1.x + b1.x, a1.y + b1.y, a1.z + b1.z, a1.w + b1.w};
  float s = 0.f, sq = 0.f;
#pragma unroll
  for (int j = 0; j < 8; ++j) { s += x[j]; sq += x[j] * x[j]; }
#pragma unroll
  for (int mask = 1; mask < 64; mask <<= 1) {
    s += __shfl_xor(s, mask);
    sq += __shfl_xor(sq, mask);
  }
  const float mean = s * (1.0f / 512.0f);
  const float var = sq * (1.0f / 512.0f) - mean * mean;
  const float rstd = rsqrtf(var + 1e-5f);
  float4 g0 = *(const float4*)(g + lane * 8), g1 = *(const float4*)(g + lane * 8 + 4);
  float4 e0 = *(const float4*)(be + lane * 8), e1 = *(const float4*)(be + lane * 8 + 4);
  const float gg[8] = {g0.x, g0.y, g0.z, g0.w, g1.x, g1.y, g1.z, g1.w};
  const float bb[8] = {e0.x, e0.y, e0.z, e0.w, e1.x, e1.y, e1.z, e1.w};
#pragma unroll
  for (int j = 0; j < 8; ++j) {
    const float y = (x[j] - mean) * rstd * gg[j] + bb[j];
    of[base + j] = y;
    ob[base + j] = f2b(y);
  }
}

extern "C" void kernel_launch(void* const* d_in, const int* in_sizes, int n_in,
                              void* d_out, int out_size, void* d_ws, size_t ws_size,
                              hipStream_t stream) {
  (void)in_sizes; (void)n_in; (void)out_size; (void)ws_size;
  const int*   tokens = (const int*)d_in[0];
  const float* emb    = (const float*)d_in[1];
  const float* cwin   = (const float*)d_in[2];
  const float* cbin   = (const float*)d_in[3];
  const float* cwout  = (const float*)d_in[4];
  const float* cbout  = (const float*)d_in[5];
  const float* gwin   = (const float*)d_in[6];
  const float* gbin   = (const float*)d_in[7];
  const float* gwout  = (const float*)d_in[8];
  const float* gbout  = (const float*)d_in[9];
  const float* ln1g   = (const float*)d_in[10];
  const float* ln1b   = (const float*)d_in[11];
  const float* fw1    = (const float*)d_in[12];
  const float* fb1    = (const float*)d_in[13];
  const float* fw2    = (const float*)d_in[14];
  const float* fb2    = (const float*)d_in[15];
  const float* ln2g   = (const float*)d_in[16];
  const float* ln2b   = (const float*)d_in[17];
  const float* fcw    = (const float*)d_in[18];
  const float* fcb    = (const float*)d_in[19];
  float* out = (float*)d_out;

  char* ws = (char*)d_ws;
  size_t off = 0;
  auto alloc = [&](size_t bytes) -> void* {
    void* p = ws + off;
    off += (bytes + 255) & ~(size_t)255;
    return p;
  };
  u16*   xb    = (u16*)alloc((size_t)4096 * 512 * 2);
  float* xf    = (float*)alloc((size_t)4096 * 512 * 4);
  u16*   qkv1b = (u16*)alloc((size_t)4096 * 1536 * 2);   // + at1 reused as pO
  u16*   at1   = (u16*)alloc((size_t)4096 * 512 * 2);
  u16*   cab   = (u16*)alloc((size_t)4096 * 512 * 2);
  u16*   qkv2  = (u16*)alloc((size_t)4096 * 1536 * 2);
  u16*   at2   = (u16*)alloc((size_t)4096 * 512 * 2);
  float* gaf   = (float*)alloc((size_t)4096 * 512 * 4);
  float* x1f   = (float*)alloc((size_t)4096 * 512 * 4);
  u16*   x1b   = (u16*)alloc((size_t)4096 * 512 * 2);
  u16*   f1b   = (u16*)alloc((size_t)4096 * 2048 * 2);
  float* ff    = (float*)alloc((size_t)4096 * 512 * 4);
  float* x2f   = (float*)alloc((size_t)4096 * 512 * 4);
  u16*   x2b   = (u16*)alloc((size_t)4096 * 512 * 2);
  u16*   wcinb  = (u16*)alloc((size_t)1536 * 512 * 2);
  u16*   wcoutb = (u16*)alloc((size_t)512 * 512 * 2);
  u16*   wginb  = (u16*)alloc((size_t)1536 * 512 * 2);
  u16*   wgoutb = (u16*)alloc((size_t)512 * 512 * 2);
  u16*   wf1b   = (u16*)alloc((size_t)2048 * 512 * 2);
  u16*   wf2b   = (u16*)alloc((size_t)512 * 2048 * 2);
  u16*   wfcb   = (u16*)alloc((size_t)32000 * 512 * 2);

  // temporal aliases (dead by the global-attention stage)
  float* pO = (float*)qkv1b;       // 2 x 4096 x 512 f32 = 16 MB (qkv1b 12MB + at1 4MB)
  float* pm = (float*)xb;          // 2 x 8 x 4096 f32
  float* pl = pm + 2 * 8 * 4096;

  f2b_multi<<<2048, 256, 0, stream>>>(
      (const float4*)cwin, wcinb, (const float4*)cwout, wcoutb,
      (const float4*)gwin, wginb, (const float4*)gwout, wgoutb,
      (const float4*)fw1, wf1b, (const float4*)fw2, wf2b,
      (const float4*)fcw, wfcb);

  embed_pe<<<4096, 256, 0, stream>>>(tokens, emb, xf, xb);

  // chunk stage
  gemm_bt<128, 0, 0, 1><<<384, 256, 0, stream>>>(xb, wcinb, cbin, (float*)nullptr, qkv1b, 4096, 1536, 512);
  chunk_attn<<<dim3(1024, 8), 64, 0, stream>>>(qkv1b, at1);
  gemm_bt<64, 0, 0, 1><<<256, 256, 0, stream>>>(at1, wcoutb, cbout, (float*)nullptr, cab, 4096, 512, 512);

  // global stage (xb/qkv1b/at1 dead after cab)
  gemm_bt<128, 0, 0, 1><<<384, 256, 0, stream>>>(cab, wginb, gbin, (float*)nullptr, qkv2, 4096, 1536, 512);
  flash_attn<<<dim3(32, 8, 2), 512, 0, stream>>>(qkv2, pO, pm, pl);
  attn_merge<<<1024, 256, 0, stream>>>(pO, pm, pl, at2);
  gemm_bt<64, 0, 1, 0><<<256, 256, 0, stream>>>(at2, wgoutb, gbout, gaf, (u16*)nullptr, 4096, 512, 512);

  // post-norm encoder layer
  add_ln<<<1024, 256, 0, stream>>>(xf, gaf, ln1g, ln1b, x1f, x1b);
  gemm_bt<128, 1, 0, 1><<<512, 256, 0, stream>>>(x1b, wf1b, fb1, (float*)nullptr, f1b, 4096, 2048, 512);
  gemm_bt<64, 0, 1, 0><<<256, 256, 0, stream>>>(f1b, wf2b, fb2, ff, (u16*)nullptr, 4096, 512, 2048);
  add_ln<<<1024, 256, 0, stream>>>(x1f, ff, ln2g, ln2b, x2f, x2b);

  // vocab projection: 2000-block 256^2 pipeline + nontemporal stores
  gemm256<512><<<2000, 512, 0, stream>>>(x2b, wfcb, fcb, out, 4096, 32000);
}

// Round 8
// 441.069 us; speedup vs baseline: 1.1400x; 1.0284x over previous
//
#include <hip/hip_runtime.h>

typedef __attribute__((ext_vector_type(8))) short bf16x8;
typedef __attribute__((ext_vector_type(4))) float f32x4;
typedef unsigned short u16;

__device__ __forceinline__ u16 f2b(float f) {
  union { float f; unsigned u; } v; v.f = f;
  return (u16)((v.u + 0x7FFFu + ((v.u >> 16) & 1u)) >> 16);
}
__device__ __forceinline__ float b2f(u16 x) {
  union { unsigned u; float f; } v; v.u = (unsigned)x << 16; return v.f;
}

__device__ __forceinline__ void gload16(const void* g, void* l) {
  __builtin_amdgcn_global_load_lds((__attribute__((address_space(1))) void*)(g),
                                   (__attribute__((address_space(3))) void*)(l),
                                   16, 0, 0);
}

__device__ __forceinline__ void mbar() {
  asm volatile("" ::: "memory");
  __builtin_amdgcn_s_barrier();
  asm volatile("" ::: "memory");
}

// ---------------- batched fp32 -> bf16 (all 7 weight tensors, one launch) ----------------
__device__ __forceinline__ void cv1(const float4* __restrict__ s, u16* __restrict__ d, int i) {
  float4 v = s[i];
  unsigned long long pk = (unsigned long long)f2b(v.x) |
                          ((unsigned long long)f2b(v.y) << 16) |
                          ((unsigned long long)f2b(v.z) << 32) |
                          ((unsigned long long)f2b(v.w) << 48);
  *(unsigned long long*)(d + (size_t)i * 4) = pk;
}

__global__ __launch_bounds__(256)
void f2b_multi(const float4* s0, u16* d0, const float4* s1, u16* d1,
               const float4* s2, u16* d2, const float4* s3, u16* d3,
               const float4* s4, u16* d4, const float4* s5, u16* d5,
               const float4* s6, u16* d6) {
  int i = blockIdx.x * 256 + threadIdx.x;
  const int stride = gridDim.x * 256;
  for (; i < 5144576; i += stride) {
    int j = i;
    if (j < 196608) { cv1(s0, d0, j); continue; }
    j -= 196608;
    if (j < 65536) { cv1(s1, d1, j); continue; }
    j -= 65536;
    if (j < 196608) { cv1(s2, d2, j); continue; }
    j -= 196608;
    if (j < 65536) { cv1(s3, d3, j); continue; }
    j -= 65536;
    if (j < 262144) { cv1(s4, d4, j); continue; }
    j -= 262144;
    if (j < 262144) { cv1(s5, d5, j); continue; }
    j -= 262144;
    cv1(s6, d6, j);
  }
}

// ---------------- embedding * sqrt(D) + sinusoidal PE ----------------
__global__ __launch_bounds__(256) void embed_pe(const int* __restrict__ tok,
    const float* __restrict__ emb, float* __restrict__ xf, u16* __restrict__ xb) {
  const int s = blockIdx.x;
  const int i = threadIdx.x;
  const int t = tok[s];
  const float div = __expf((float)(2 * i) * -0.017988946039015984f);
  const float ang = (float)s * div;
  const float sv = __sinf(ang), cv = __cosf(ang);
  const float* e = emb + (size_t)t * 512 + 2 * i;
  const float x0 = e[0] * 22.627416997969522f + sv;
  const float x1 = e[1] * 22.627416997969522f + cv;
  const size_t o = (size_t)s * 512 + 2 * i;
  xf[o] = x0; xf[o + 1] = x1;
  xb[o] = f2b(x0); xb[o + 1] = f2b(x1);
}

// ---------------- tiled GEMM: C = A(MxK) . B(NxK)^T + bias; BK=64, swizzled LDS ----------------
template<int BM, int RELU, int WF32, int WB16>
__global__ __launch_bounds__(256)
void gemm_bt(const u16* __restrict__ A, const u16* __restrict__ B,
             const float* __restrict__ bias, float* __restrict__ Cf,
             u16* __restrict__ Cb, int M, int N, int K)
{
  constexpr int MFR = BM / 32;
  __shared__ __align__(16) u16 As[BM * 64];
  __shared__ __align__(16) u16 Bs[128 * 64];
  const int tid = threadIdx.x;
  const int wid = tid >> 6, lane = tid & 63;
  const int lo = lane & 15, hi = lane >> 4;
  const int nbn = N >> 7;
  const int cpx = (int)gridDim.x >> 3;
  const int bid = blockIdx.x;
  const int swz = (bid & 7) * cpx + (bid >> 3);
  const int bi = swz / nbn, bj = swz - bi * nbn;
  const size_t row0 = (size_t)bi * BM, col0 = (size_t)bj << 7;
  const int wr = (wid >> 1) * (BM / 2), wc = (wid & 1) << 6;
  const int srow = (wid << 3) + (lane >> 3);
  const int scol = ((lane & 7) ^ (lane >> 3)) << 3;

  f32x4 acc[MFR][4] = {};

  auto rdA = [&](int row, int ks) -> bf16x8 {
    return *(const bf16x8*)((const char*)As + row * 128 + ((((ks << 2) | hi) ^ (row & 7)) << 4));
  };
  auto rdB = [&](int row, int ks) -> bf16x8 {
    return *(const bf16x8*)((const char*)Bs + row * 128 + ((((ks << 2) | hi) ^ (row & 7)) << 4));
  };

  for (int k0 = 0; k0 < K; k0 += 64) {
    __syncthreads();
#pragma unroll
    for (int p = 0; p < BM / 32; ++p)
      gload16(A + (row0 + srow + 32 * p) * (size_t)K + k0 + scol, &As[(wid * 8 + 32 * p) * 64]);
#pragma unroll
    for (int p = 0; p < 4; ++p)
      gload16(B + (col0 + srow + 32 * p) * (size_t)K + k0 + scol, &Bs[(wid * 8 + 32 * p) * 64]);
    __syncthreads();
#pragma unroll
    for (int ks = 0; ks < 2; ++ks) {
      bf16x8 af[MFR], bfr[4];
#pragma unroll
      for (int m = 0; m < MFR; ++m) af[m] = rdA(wr + m * 16 + lo, ks);
#pragma unroll
      for (int n = 0; n < 4; ++n) bfr[n] = rdB(wc + n * 16 + lo, ks);
#pragma unroll
      for (int m = 0; m < MFR; ++m)
#pragma unroll
        for (int n = 0; n < 4; ++n)
          acc[m][n] = __builtin_amdgcn_mfma_f32_16x16x32_bf16(af[m], bfr[n], acc[m][n], 0, 0, 0);
    }
  }

#pragma unroll
  for (int m = 0; m < MFR; ++m)
#pragma unroll
    for (int n = 0; n < 4; ++n) {
      const size_t c = col0 + wc + n * 16 + lo;
      const float bv = bias[c];
#pragma unroll
      for (int i = 0; i < 4; ++i) {
        const size_t r = row0 + wr + m * 16 + hi * 4 + i;
        float v = acc[m][n][i] + bv;
        if (RELU) v = fmaxf(v, 0.0f);
        if (WF32) Cf[r * (size_t)N + c] = v;
        if (WB16) Cb[r * (size_t)N + c] = f2b(v);
      }
    }
}

// ---------------- 256x256 8-phase GEMM (FC), 2000 blocks, split-phase epilogue ----------------
template<int KC>
__global__ __launch_bounds__(512, 2)
void gemm256(const u16* __restrict__ A, const u16* __restrict__ B,
             const float* __restrict__ bias, float* __restrict__ C,
             int M, int N)
{
  constexpr int T = KC / 64;
  __shared__ __align__(16) u16 LA[2][256 * 64];
  __shared__ __align__(16) u16 LB[2][256 * 64];
  const int tid = threadIdx.x;
  const int wid = tid >> 6, lane = tid & 63;
  const int lo = lane & 15, hi = lane >> 4;
  const int nbn = N >> 8;
  const int cpx = (int)gridDim.x >> 3;
  const int bid = blockIdx.x;
  const int swz = (bid & 7) * cpx + (bid >> 3);
  const int bi = swz / nbn, bj = swz - bi * nbn;
  const size_t row0 = (size_t)bi << 8, col0 = (size_t)bj << 8;
  const int wrow = (wid >> 2) << 7;
  const int wcol = (wid & 3) << 6;

  const int srow = (wid << 3) + (lane >> 3);
  const int scol = ((lane & 7) ^ (lane >> 3)) << 3;
  const u16* srcA = A + (row0 + srow) * (size_t)KC + scol;
  const u16* srcB = B + (col0 + srow) * (size_t)KC + scol;
  const int ldst = wid << 9;

  f32x4 acc[8][4] = {};

  auto stage = [&](int t, int b) {
    const size_t ko = (size_t)t * 64;
#pragma unroll
    for (int i = 0; i < 4; ++i)
      gload16(srcA + ko + (size_t)(i * 64) * KC, &LA[b][ldst + i * 4096]);
#pragma unroll
    for (int i = 0; i < 4; ++i)
      gload16(srcB + ko + (size_t)(i * 64) * KC, &LB[b][ldst + i * 4096]);
  };

  auto rd = [&](const u16* base, int row, int ks) -> bf16x8 {
    const int byte = row * 128 + ((((ks << 2) | hi) ^ (row & 7)) << 4);
    return *(const bf16x8*)((const char*)base + byte);
  };

  auto storeHalf = [&](int mbase) {   // stores acc[mbase..mbase+3] (rows final)
#pragma unroll
    for (int m = 0; m < 4; ++m)
#pragma unroll
      for (int n = 0; n < 4; ++n) {
        const size_t c = col0 + wcol + n * 16 + lo;
        const float bv = bias[c];
#pragma unroll
        for (int i = 0; i < 4; ++i) {
          const size_t r = row0 + wrow + (mbase + m) * 16 + hi * 4 + i;
          __builtin_nontemporal_store(acc[mbase + m][n][i] + bv, &C[r * (size_t)N + c]);
        }
      }
  };

  stage(0, 0);
  stage(1, 1);

  for (int t = 0; t < T - 1; ++t) {
    const int b = t & 1;
    const u16* Ab = LA[b];
    const u16* Bb = LB[b];
    asm volatile("s_waitcnt vmcnt(8)" ::: "memory");
    __builtin_amdgcn_sched_barrier(0);
    mbar();

    bf16x8 afr[4], bfr[4];
#pragma unroll
    for (int ks = 0; ks < 2; ++ks) {
#pragma unroll
      for (int m = 0; m < 4; ++m) afr[m] = rd(Ab, wrow + m * 16 + lo, ks);
#pragma unroll
      for (int n = 0; n < 4; ++n) bfr[n] = rd(Bb, wcol + n * 16 + lo, ks);
      mbar();
      asm volatile("s_waitcnt lgkmcnt(0)" ::: "memory");
      __builtin_amdgcn_sched_barrier(0);
      __builtin_amdgcn_s_setprio(1);
#pragma unroll
      for (int m = 0; m < 4; ++m)
#pragma unroll
        for (int n = 0; n < 4; ++n)
          acc[m][n] = __builtin_amdgcn_mfma_f32_16x16x32_bf16(afr[m], bfr[n], acc[m][n], 0, 0, 0);
      __builtin_amdgcn_s_setprio(0);
      mbar();
#pragma unroll
      for (int m = 0; m < 4; ++m) afr[m] = rd(Ab, wrow + (4 + m) * 16 + lo, ks);
      mbar();
      asm volatile("s_waitcnt lgkmcnt(0)" ::: "memory");
      __builtin_amdgcn_sched_barrier(0);
      __builtin_amdgcn_s_setprio(1);
#pragma unroll
      for (int m = 0; m < 4; ++m)
#pragma unroll
        for (int n = 0; n < 4; ++n)
          acc[4 + m][n] = __builtin_amdgcn_mfma_f32_16x16x32_bf16(afr[m], bfr[n], acc[4 + m][n], 0, 0, 0);
      __builtin_amdgcn_s_setprio(0);
      mbar();
    }
    if (t + 2 < T) stage(t + 2, b);
  }

  // ---- peeled last tile: stores for acc[0..3] issue right after their final MFMA ----
  {
    const u16* Ab = LA[(T - 1) & 1];
    const u16* Bb = LB[(T - 1) & 1];
    asm volatile("s_waitcnt vmcnt(0)" ::: "memory");
    __builtin_amdgcn_sched_barrier(0);
    mbar();

    bf16x8 afr[4], bfr[4];
    // ks = 0 (both halves, no stores yet)
#pragma unroll
    for (int m = 0; m < 4; ++m) afr[m] = rd(Ab, wrow + m * 16 + lo, 0);
#pragma unroll
    for (int n = 0; n < 4; ++n) bfr[n] = rd(Bb, wcol + n * 16 + lo, 0);
    mbar();
    asm volatile("s_waitcnt lgkmcnt(0)" ::: "memory");
    __builtin_amdgcn_sched_barrier(0);
#pragma unroll
    for (int m = 0; m < 4; ++m)
#pragma unroll
      for (int n = 0; n < 4; ++n)
        acc[m][n] = __builtin_amdgcn_mfma_f32_16x16x32_bf16(afr[m], bfr[n], acc[m][n], 0, 0, 0);
    mbar();
#pragma unroll
    for (int m = 0; m < 4; ++m) afr[m] = rd(Ab, wrow + (4 + m) * 16 + lo, 0);
    mbar();
    asm volatile("s_waitcnt lgkmcnt(0)" ::: "memory");
    __builtin_amdgcn_sched_barrier(0);
#pragma unroll
    for (int m = 0; m < 4; ++m)
#pragma unroll
      for (int n = 0; n < 4; ++n)
        acc[4 + m][n] = __builtin_amdgcn_mfma_f32_16x16x32_bf16(afr[m], bfr[n], acc[4 + m][n], 0, 0, 0);
    mbar();
    // ks = 1: finish m0-3, store them, then finish m4-7, store
#pragma unroll
    for (int m = 0; m < 4; ++m) afr[m] = rd(Ab, wrow + m * 16 + lo, 1);
#pragma unroll
    for (int n = 0; n < 4; ++n) bfr[n] = rd(Bb, wcol + n * 16 + lo, 1);
    asm volatile("s_waitcnt lgkmcnt(0)" ::: "memory");
    __builtin_amdgcn_sched_barrier(0);
#pragma unroll
    for (int m = 0; m < 4; ++m)
#pragma unroll
      for (int n = 0; n < 4; ++n)
        acc[m][n] = __builtin_amdgcn_mfma_f32_16x16x32_bf16(afr[m], bfr[n], acc[m][n], 0, 0, 0);
    storeHalf(0);      // 131 KB/block starts draining under the remaining compute
#pragma unroll
    for (int m = 0; m < 4; ++m) afr[m] = rd(Ab, wrow + (4 + m) * 16 + lo, 1);
    asm volatile("s_waitcnt lgkmcnt(0)" ::: "memory");
    __builtin_amdgcn_sched_barrier(0);
#pragma unroll
    for (int m = 0; m < 4; ++m)
#pragma unroll
      for (int n = 0; n < 4; ++n)
        acc[4 + m][n] = __builtin_amdgcn_mfma_f32_16x16x32_bf16(afr[m], bfr[n], acc[4 + m][n], 0, 0, 0);
    storeHalf(4);
  }
}

// ---------------- chunk attention: attend over nc=4 chunks (bf16 qkv) ----------------
__global__ __launch_bounds__(64)
void chunk_attn(const u16* __restrict__ qkv, u16* __restrict__ out) {
  const int p = blockIdx.x, h = blockIdx.y, d = threadIdx.x;
  float q[4], k[4], v[4];
#pragma unroll
  for (int c = 0; c < 4; ++c) {
    const u16* b = qkv + (size_t)((c << 10) + p) * 1536 + (h << 6) + d;
    q[c] = b2f(b[0]); k[c] = b2f(b[512]); v[c] = b2f(b[1024]);
  }
  float sc[4][4];
#pragma unroll
  for (int i = 0; i < 4; ++i)
#pragma unroll
    for (int j = 0; j < 4; ++j) sc[i][j] = q[i] * k[j];
#pragma unroll
  for (int mask = 1; mask < 64; mask <<= 1)
#pragma unroll
    for (int i = 0; i < 4; ++i)
#pragma unroll
      for (int j = 0; j < 4; ++j) sc[i][j] += __shfl_xor(sc[i][j], mask);
#pragma unroll
  for (int i = 0; i < 4; ++i) {
    float s0 = sc[i][0] * 0.125f, s1 = sc[i][1] * 0.125f,
          s2 = sc[i][2] * 0.125f, s3 = sc[i][3] * 0.125f;
    const float mx = fmaxf(fmaxf(s0, s1), fmaxf(s2, s3));
    const float e0 = __expf(s0 - mx), e1 = __expf(s1 - mx),
                e2 = __expf(s2 - mx), e3 = __expf(s3 - mx);
    const float inv = 1.0f / (e0 + e1 + e2 + e3);
    const float o = (e0 * v[0] + e1 * v[1] + e2 * v[2] + e3 * v[3]) * inv;
    out[(size_t)((i << 10) + p) * 512 + (h << 6) + d] = f2b(o);
  }
}

// ---------------- global flash attention: KV-split x2, swapped QK^T ----------------
__global__ __launch_bounds__(512, 4)
void flash_attn(const u16* __restrict__ qkv, float* __restrict__ pO,
                float* __restrict__ pm, float* __restrict__ pl) {
  __shared__ __align__(16) u16 Ks[64 * 64];
  __shared__ __align__(16) u16 Vt[64 * 64];
  __shared__ __align__(16) u16 Pp[8][16 * 64];
  const int tid = threadIdx.x, wid = tid >> 6, lane = tid & 63;
  const int lo = lane & 15, hi = lane >> 4;
  const int q0 = blockIdx.x << 7, h = blockIdx.y, z = blockIdx.z;
  const int kvb = z << 11;
  const int hoff = h << 6;
  char* KsB = (char*)Ks; char* VtB = (char*)Vt;
  char* Pw = (char*)&Pp[wid][0];
  const int xsw = (lo & 7) << 4;
  constexpr float C1 = 0.18033688011112042f;

  bf16x8 qf[2];
#pragma unroll
  for (int kh = 0; kh < 2; ++kh)
    qf[kh] = *(const bf16x8*)(qkv + (size_t)(q0 + wid * 16 + lo) * 1536 + hoff + kh * 32 + hi * 8);

  f32x4 o[4] = {};
  float mr = -3e38f, lr = 0.f;

  const int krow = tid >> 3, kq = tid & 7;

  bf16x8 kpre = *(const bf16x8*)(qkv + (size_t)(kvb + krow) * 1536 + 512 + hoff + kq * 8);
  bf16x8 vpre = *(const bf16x8*)(qkv + (size_t)(kvb + krow) * 1536 + 1024 + hoff + kq * 8);

  for (int kv0 = kvb; kv0 < kvb + 2048; kv0 += 64) {
    __syncthreads();
    *(bf16x8*)(KsB + ((krow * 128 + kq * 16) ^ ((krow & 7) << 4))) = kpre;
    {
      const unsigned* vp = (const unsigned*)&vpre;
      const int oddr = krow & 1;
      const unsigned t0 = oddr ? vp[0] : vp[2];
      const unsigned t1 = oddr ? vp[1] : vp[3];
      const unsigned r0 = (unsigned)__shfl_xor((int)t0, 8);
      const unsigned r1 = (unsigned)__shfl_xor((int)t1, 8);
      const unsigned E0 = oddr ? r0 : vp[0];
      const unsigned E1 = oddr ? r1 : vp[1];
      const unsigned O0 = oddr ? vp[2] : r0;
      const unsigned O1 = oddr ? vp[3] : r1;
      const int jp = krow & ~1;
      const int db = kq * 8 + oddr * 4;
      unsigned w0 = (E0 & 0xffffu) | (O0 << 16);
      unsigned w1 = (E0 >> 16) | (O0 & 0xffff0000u);
      unsigned w2 = (E1 & 0xffffu) | (O1 << 16);
      unsigned w3 = (E1 >> 16) | (O1 & 0xffff0000u);
      *(unsigned*)(VtB + (((db + 0) * 128 + 2 * jp) ^ (((db + 0) & 7) << 4))) = w0;
      *(unsigned*)(VtB + (((db + 1) * 128 + 2 * jp) ^ (((db + 1) & 7) << 4))) = w1;
      *(unsigned*)(VtB + (((db + 2) * 128 + 2 * jp) ^ (((db + 2) & 7) << 4))) = w2;
      *(unsigned*)(VtB + (((db + 3) * 128 + 2 * jp) ^ (((db + 3) & 7) << 4))) = w3;
    }
    __syncthreads();
    if (kv0 + 64 < kvb + 2048) {
      kpre = *(const bf16x8*)(qkv + (size_t)(kv0 + 64 + krow) * 1536 + 512 + hoff + kq * 8);
      vpre = *(const bf16x8*)(qkv + (size_t)(kv0 + 64 + krow) * 1536 + 1024 + hoff + kq * 8);
    }

    f32x4 s[4] = {};
#pragma unroll
    for (int n = 0; n < 4; ++n) {
      const int key = n * 16 + lo;
#pragma unroll
      for (int kh = 0; kh < 2; ++kh) {
        bf16x8 kf = *(const bf16x8*)(KsB + ((key * 128 + kh * 64 + hi * 16) ^ ((key & 7) << 4)));
        s[n] = __builtin_amdgcn_mfma_f32_16x16x32_bf16(kf, qf[kh], s[n], 0, 0, 0);
      }
    }

    float pmx = s[0][0];
#pragma unroll
    for (int n = 0; n < 4; ++n)
#pragma unroll
      for (int i = 0; i < 4; ++i) pmx = fmaxf(pmx, s[n][i]);
    pmx = fmaxf(pmx, __shfl_xor(pmx, 16));
    pmx = fmaxf(pmx, __shfl_xor(pmx, 32));

    if (__any(pmx > mr + 64.f)) {
      const float mn = fmaxf(mr, pmx);
      const float sc = exp2f((mr - mn) * C1);
      mr = mn;
      lr *= sc;
#pragma unroll
      for (int i = 0; i < 4; ++i) {
        const float sq = __shfl(sc, hi * 4 + i);
#pragma unroll
        for (int n = 0; n < 4; ++n) o[n][i] *= sq;
      }
    }

    const float mc = mr * C1;
    float rs = 0.f;
    unsigned U[8];
#pragma unroll
    for (int n = 0; n < 4; ++n) {
      const float p0 = exp2f(fmaf(s[n][0], C1, -mc));
      const float p1 = exp2f(fmaf(s[n][1], C1, -mc));
      const float p2 = exp2f(fmaf(s[n][2], C1, -mc));
      const float p3 = exp2f(fmaf(s[n][3], C1, -mc));
      rs += (p0 + p1) + (p2 + p3);
      asm("v_cvt_pk_bf16_f32 %0, %1, %2" : "=v"(U[2 * n])     : "v"(p0), "v"(p1));
      asm("v_cvt_pk_bf16_f32 %0, %1, %2" : "=v"(U[2 * n + 1]) : "v"(p2), "v"(p3));
    }
    rs += __shfl_xor(rs, 16);
    rs += __shfl_xor(rs, 32);
    lr += rs;
#pragma unroll
    for (int n = 0; n < 4; ++n) {
      const int off = lo * 128 + ((n * 32 + hi * 8) ^ xsw);
      const unsigned long long dw = (unsigned long long)U[2 * n] |
                                    ((unsigned long long)U[2 * n + 1] << 32);
      *(unsigned long long*)(Pw + off) = dw;
    }

#pragma unroll
    for (int kh = 0; kh < 2; ++kh) {
      bf16x8 pa = *(const bf16x8*)(Pw + lo * 128 + ((kh * 64 + hi * 16) ^ xsw));
#pragma unroll
      for (int n = 0; n < 4; ++n) {
        const int vd = n * 16 + lo;
        bf16x8 vf = *(const bf16x8*)(VtB + ((vd * 128 + kh * 64 + hi * 16) ^ ((vd & 7) << 4)));
        o[n] = __builtin_amdgcn_mfma_f32_16x16x32_bf16(pa, vf, o[n], 0, 0, 0);
      }
    }
  }

#pragma unroll
  for (int i = 0; i < 4; ++i) {
    const int r = q0 + wid * 16 + hi * 4 + i;
#pragma unroll
    for (int n = 0; n < 4; ++n)
      pO[((size_t)z * 4096 + r) * 512 + hoff + n * 16 + lo] = o[n][i];
  }
  if (hi == 0) {
    const int r = q0 + wid * 16 + lo;
    pm[(z * 8 + h) * 4096 + r] = mr;
    pl[(z * 8 + h) * 4096 + r] = lr;
  }
}

// ---------------- merge the two KV-half partials ----------------
__global__ __launch_bounds__(256)
void attn_merge(const float* __restrict__ pO, const float* __restrict__ pm,
                const float* __restrict__ pl, u16* __restrict__ out) {
  constexpr float C1 = 0.18033688011112042f;
  const int tid = threadIdx.x, lane = tid & 63, w = tid >> 6;
  const int row = blockIdx.x * 4 + w;
  const int d = lane * 8, h = lane >> 3;
  const float m0 = pm[h * 4096 + row], m1 = pm[(8 + h) * 4096 + row];
  const float l0 = pl[h * 4096 + row], l1 = pl[(8 + h) * 4096 + row];
  const float M = fmaxf(m0, m1);
  const float w0 = exp2f((m0 - M) * C1), w1 = exp2f((m1 - M) * C1);
  const float inv = 1.0f / (l0 * w0 + l1 * w1);
  const float* a = pO + (size_t)row * 512 + d;
  const float* b = pO + ((size_t)4096 + row) * 512 + d;
  float4 a0 = *(const float4*)a, a1 = *(const float4*)(a + 4);
  float4 b0 = *(const float4*)b, b1 = *(const float4*)(b + 4);
  const float A[8] = {a0.x, a0.y, a0.z, a0.w, a1.x, a1.y, a1.z, a1.w};
  const float Bv[8] = {b0.x, b0.y, b0.z, b0.w, b1.x, b1.y, b1.z, b1.w};
#pragma unroll
  for (int j = 0; j < 8; ++j)
    out[(size_t)row * 512 + d + j] = f2b((A[j] * w0 + Bv[j] * w1) * inv);
}

// ---------------- residual add + LayerNorm ----------------
__global__ __launch_bounds__(256)
void add_ln(const float* __restrict__ a, const float* __restrict__ b,
            const float* __restrict__ g, const float* __restrict__ be,
            float* __restrict__ of, u16* __restrict__ ob) {
  const int wid = threadIdx.x >> 6, lane = threadIdx.x & 63;
  const int row = blockIdx.x * 4 + wid;
  const size_t base = (size_t)row * 512 + lane * 8;
  float4 a0 = *(const float4*)(a + base), a1 = *(const float4*)(a + base + 4);
  float4 b0 = *(const float4*)(b + base), b1 = *(const float4*)(b + base + 4);
  float x[8] = {a0.x + b0.x, a0.y + b0.y, a0.z + b0.z, a0.w + b0.w,
                a1.x + b1.x, a1.y + b1.y, a1.z + b1.z, a1.w + b1.w};
  float s = 0.f, sq = 0.f;
#pragma unroll
  for (int j = 0; j < 8; ++j) { s += x[j]; sq += x[j] * x[j]; }
#pragma unroll
  for (int mask = 1; mask < 64; mask <<= 1) {
    s += __shfl_xor(s, mask);
    sq += __shfl_xor(sq, mask);
  }
  const float mean = s * (1.0f / 512.0f);
  const float var = sq * (1.0f / 512.0f) - mean * mean;
  const float rstd = rsqrtf(var + 1e-5f);
  float4 g0 = *(const float4*)(g + lane * 8), g1 = *(const float4*)(g + lane * 8 + 4);
  float4 e0 = *(const float4*)(be + lane * 8), e1 = *(const float4*)(be + lane * 8 + 4);
  const float gg[8] = {g0.x, g0.y, g0.z, g0.w, g1.x, g1.y, g1.z, g1.w};
  const float bb[8] = {e0.x, e0.y, e0.z, e0.w, e1.x, e1.y, e1.z, e1.w};
#pragma unroll
  for (int j = 0; j < 8; ++j) {
    const float y = (x[j] - mean) * rstd * gg[j] + bb[j];
    of[base + j] = y;
    ob[base + j] = f2b(y);
  }
}

extern "C" void kernel_launch(void* const* d_in, const int* in_sizes, int n_in,
                              void* d_out, int out_size, void* d_ws, size_t ws_size,
                              hipStream_t stream) {
  (void)in_sizes; (void)n_in; (void)out_size; (void)ws_size;
  const int*   tokens = (const int*)d_in[0];
  const float* emb    = (const float*)d_in[1];
  const float* cwin   = (const float*)d_in[2];
  const float* cbin   = (const float*)d_in[3];
  const float* cwout  = (const float*)d_in[4];
  const float* cbout  = (const float*)d_in[5];
  const float* gwin   = (const float*)d_in[6];
  const float* gbin   = (const float*)d_in[7];
  const float* gwout  = (const float*)d_in[8];
  const float* gbout  = (const float*)d_in[9];
  const float* ln1g   = (const float*)d_in[10];
  const float* ln1b   = (const float*)d_in[11];
  const float* fw1    = (const float*)d_in[12];
  const float* fb1    = (const float*)d_in[13];
  const float* fw2    = (const float*)d_in[14];
  const float* fb2    = (const float*)d_in[15];
  const float* ln2g   = (const float*)d_in[16];
  const float* ln2b   = (const float*)d_in[17];
  const float* fcw    = (const float*)d_in[18];
  const float* fcb    = (const float*)d_in[19];
  float* out = (float*)d_out;

  char* ws = (char*)d_ws;
  size_t off = 0;
  auto alloc = [&](size_t bytes) -> void* {
    void* p = ws + off;
    off += (bytes + 255) & ~(size_t)255;
    return p;
  };
  u16*   xb    = (u16*)alloc((size_t)4096 * 512 * 2);
  float* xf    = (float*)alloc((size_t)4096 * 512 * 4);
  u16*   qkv1b = (u16*)alloc((size_t)4096 * 1536 * 2);   // + at1 reused as pO
  u16*   at1   = (u16*)alloc((size_t)4096 * 512 * 2);
  u16*   cab   = (u16*)alloc((size_t)4096 * 512 * 2);
  u16*   qkv2  = (u16*)alloc((size_t)4096 * 1536 * 2);
  u16*   at2   = (u16*)alloc((size_t)4096 * 512 * 2);
  float* gaf   = (float*)alloc((size_t)4096 * 512 * 4);
  float* x1f   = (float*)alloc((size_t)4096 * 512 * 4);
  u16*   x1b   = (u16*)alloc((size_t)4096 * 512 * 2);
  u16*   f1b   = (u16*)alloc((size_t)4096 * 2048 * 2);
  float* ff    = (float*)alloc((size_t)4096 * 512 * 4);
  float* x2f   = (float*)alloc((size_t)4096 * 512 * 4);
  u16*   x2b   = (u16*)alloc((size_t)4096 * 512 * 2);
  u16*   wcinb  = (u16*)alloc((size_t)1536 * 512 * 2);
  u16*   wcoutb = (u16*)alloc((size_t)512 * 512 * 2);
  u16*   wginb  = (u16*)alloc((size_t)1536 * 512 * 2);
  u16*   wgoutb = (u16*)alloc((size_t)512 * 512 * 2);
  u16*   wf1b   = (u16*)alloc((size_t)2048 * 512 * 2);
  u16*   wf2b   = (u16*)alloc((size_t)512 * 2048 * 2);
  u16*   wfcb   = (u16*)alloc((size_t)32000 * 512 * 2);

  // temporal aliases (dead by the global-attention stage)
  float* pO = (float*)qkv1b;       // 2 x 4096 x 512 f32 = 16 MB (qkv1b 12MB + at1 4MB)
  float* pm = (float*)xb;          // 2 x 8 x 4096 f32
  float* pl = pm + 2 * 8 * 4096;

  f2b_multi<<<2048, 256, 0, stream>>>(
      (const float4*)cwin, wcinb, (const float4*)cwout, wcoutb,
      (const float4*)gwin, wginb, (const float4*)gwout, wgoutb,
      (const float4*)fw1, wf1b, (const float4*)fw2, wf2b,
      (const float4*)fcw, wfcb);

  embed_pe<<<4096, 256, 0, stream>>>(tokens, emb, xf, xb);

  // chunk stage (BM=64 -> grid 768 = 3.0 full CU rounds)
  gemm_bt<64, 0, 0, 1><<<768, 256, 0, stream>>>(xb, wcinb, cbin, (float*)nullptr, qkv1b, 4096, 1536, 512);
  chunk_attn<<<dim3(1024, 8), 64, 0, stream>>>(qkv1b, at1);
  gemm_bt<64, 0, 0, 1><<<256, 256, 0, stream>>>(at1, wcoutb, cbout, (float*)nullptr, cab, 4096, 512, 512);

  // global stage
  gemm_bt<64, 0, 0, 1><<<768, 256, 0, stream>>>(cab, wginb, gbin, (float*)nullptr, qkv2, 4096, 1536, 512);
  flash_attn<<<dim3(32, 8, 2), 512, 0, stream>>>(qkv2, pO, pm, pl);
  attn_merge<<<1024, 256, 0, stream>>>(pO, pm, pl, at2);
  gemm_bt<64, 0, 1, 0><<<256, 256, 0, stream>>>(at2, wgoutb, gbout, gaf, (u16*)nullptr, 4096, 512, 512);

  // post-norm encoder layer (FFN1 BM=64 -> grid 1024 = 4.0 rounds)
  add_ln<<<1024, 256, 0, stream>>>(xf, gaf, ln1g, ln1b, x1f, x1b);
  gemm_bt<64, 1, 0, 1><<<1024, 256, 0, stream>>>(x1b, wf1b, fb1, (float*)nullptr, f1b, 4096, 2048, 512);
  gemm_bt<64, 0, 1, 0><<<256, 256, 0, stream>>>(f1b, wf2b, fb2, ff, (u16*)nullptr, 4096, 512, 2048);
  add_ln<<<1024, 256, 0, stream>>>(x1f, ff, ln2g, ln2b, x2f, x2b);

  // vocab projection: 2000-block 256^2 pipeline, split-phase nt epilogue
  gemm256<512><<<2000, 512, 0, stream>>>(x2b, wfcb, fcb, out, 4096, 32000);
}

// Round 9
// 436.979 us; speedup vs baseline: 1.1507x; 1.0094x over previous
//
#include <hip/hip_runtime.h>

typedef __attribute__((ext_vector_type(8))) short bf16x8;
typedef __attribute__((ext_vector_type(4))) float f32x4;
typedef unsigned short u16;

__device__ __forceinline__ u16 f2b(float f) {
  union { float f; unsigned u; } v; v.f = f;
  return (u16)((v.u + 0x7FFFu + ((v.u >> 16) & 1u)) >> 16);
}
__device__ __forceinline__ float b2f(u16 x) {
  union { unsigned u; float f; } v; v.u = (unsigned)x << 16; return v.f;
}

__device__ __forceinline__ void gload16(const void* g, void* l) {
  __builtin_amdgcn_global_load_lds((__attribute__((address_space(1))) void*)(g),
                                   (__attribute__((address_space(3))) void*)(l),
                                   16, 0, 0);
}

__device__ __forceinline__ void mbar() {
  asm volatile("" ::: "memory");
  __builtin_amdgcn_s_barrier();
  asm volatile("" ::: "memory");
}

// ---------------- fused prep: embedding+PE (blocks 0..4095) | weight f2b (rest) ----------------
__device__ __forceinline__ void cv1(const float4* __restrict__ s, u16* __restrict__ d, int i) {
  float4 v = s[i];
  unsigned long long pk = (unsigned long long)f2b(v.x) |
                          ((unsigned long long)f2b(v.y) << 16) |
                          ((unsigned long long)f2b(v.z) << 32) |
                          ((unsigned long long)f2b(v.w) << 48);
  *(unsigned long long*)(d + (size_t)i * 4) = pk;
}

__global__ __launch_bounds__(256)
void prep(const int* __restrict__ tok, const float* __restrict__ emb,
          float* __restrict__ xf, u16* __restrict__ xb,
          const float4* s0, u16* d0, const float4* s1, u16* d1,
          const float4* s2, u16* d2, const float4* s3, u16* d3,
          const float4* s4, u16* d4, const float4* s5, u16* d5,
          const float4* s6, u16* d6) {
  if (blockIdx.x < 4096) {
    const int s = blockIdx.x;
    const int i = threadIdx.x;
    const int t = tok[s];
    const float div = __expf((float)(2 * i) * -0.017988946039015984f);
    const float ang = (float)s * div;
    const float sv = __sinf(ang), cv = __cosf(ang);
    const float* e = emb + (size_t)t * 512 + 2 * i;
    const float x0 = e[0] * 22.627416997969522f + sv;
    const float x1 = e[1] * 22.627416997969522f + cv;
    const size_t o = (size_t)s * 512 + 2 * i;
    xf[o] = x0; xf[o + 1] = x1;
    xb[o] = f2b(x0); xb[o + 1] = f2b(x1);
    return;
  }
  int i = (blockIdx.x - 4096) * 256 + threadIdx.x;
  const int stride = ((int)gridDim.x - 4096) * 256;
  for (; i < 5144576; i += stride) {
    int j = i;
    if (j < 196608) { cv1(s0, d0, j); continue; }
    j -= 196608;
    if (j < 65536) { cv1(s1, d1, j); continue; }
    j -= 65536;
    if (j < 196608) { cv1(s2, d2, j); continue; }
    j -= 196608;
    if (j < 65536) { cv1(s3, d3, j); continue; }
    j -= 65536;
    if (j < 262144) { cv1(s4, d4, j); continue; }
    j -= 262144;
    if (j < 262144) { cv1(s5, d5, j); continue; }
    j -= 262144;
    cv1(s6, d6, j);
  }
}

// ---- tiled GEMM, counted-vmcnt double-buffer (gemm256 schedule at 128xBM tile) ----
// C = A(MxK,bf16) . B(NxK,bf16)^T + bias
template<int BM, int RELU, int WF32, int WB16>
__global__ __launch_bounds__(256)
void gemm_bt(const u16* __restrict__ A, const u16* __restrict__ B,
             const float* __restrict__ bias, float* __restrict__ Cf,
             u16* __restrict__ Cb, int M, int N, int K)
{
  constexpr int MFR = BM / 32;
  __shared__ __align__(16) u16 As[2][BM * 64];
  __shared__ __align__(16) u16 Bs[2][128 * 64];
  const int tid = threadIdx.x;
  const int wid = tid >> 6, lane = tid & 63;
  const int lo = lane & 15, hi = lane >> 4;
  const int nbn = N >> 7;
  const int cpx = (int)gridDim.x >> 3;
  const int bid = blockIdx.x;
  const int swz = (bid & 7) * cpx + (bid >> 3);
  const int bi = swz / nbn, bj = swz - bi * nbn;
  const size_t row0 = (size_t)bi * BM, col0 = (size_t)bj << 7;
  const int wr = (wid >> 1) * (BM / 2), wc = (wid & 1) << 6;
  const int srow = (wid << 3) + (lane >> 3);
  const int scol = ((lane & 7) ^ (lane >> 3)) << 3;

  f32x4 acc[MFR][4] = {};

  auto stage = [&](int t, int b) {
    const int k0 = t << 6;
#pragma unroll
    for (int p = 0; p < BM / 32; ++p)
      gload16(A + (row0 + srow + 32 * p) * (size_t)K + k0 + scol, &As[b][(wid * 8 + 32 * p) * 64]);
#pragma unroll
    for (int p = 0; p < 4; ++p)
      gload16(B + (col0 + srow + 32 * p) * (size_t)K + k0 + scol, &Bs[b][(wid * 8 + 32 * p) * 64]);
  };

  auto rdf = [&](const u16* base, int row, int ks) -> bf16x8 {
    return *(const bf16x8*)((const char*)base + row * 128 + ((((ks << 2) | hi) ^ (row & 7)) << 4));
  };

  const int T = K >> 6;
  stage(0, 0);
  stage(1, 1);

  for (int t = 0; t < T; ++t) {
    // wait for tile t's loads only (stage t+1 stays in flight) — never drain mid-loop
    if (t + 1 < T) {
      if constexpr (BM == 64) { asm volatile("s_waitcnt vmcnt(6)" ::: "memory"); }
      else                    { asm volatile("s_waitcnt vmcnt(8)" ::: "memory"); }
    } else {
      asm volatile("s_waitcnt vmcnt(0)" ::: "memory");
    }
    __builtin_amdgcn_sched_barrier(0);
    mbar();                       // tile t visible to all waves
    const u16* Ab = As[t & 1];
    const u16* Bb = Bs[t & 1];
#pragma unroll
    for (int ks = 0; ks < 2; ++ks) {
      bf16x8 af[MFR], bfr[4];
#pragma unroll
      for (int m = 0; m < MFR; ++m) af[m] = rdf(Ab, wr + m * 16 + lo, ks);
#pragma unroll
      for (int n = 0; n < 4; ++n) bfr[n] = rdf(Bb, wc + n * 16 + lo, ks);
#pragma unroll
      for (int m = 0; m < MFR; ++m)
#pragma unroll
        for (int n = 0; n < 4; ++n)
          acc[m][n] = __builtin_amdgcn_mfma_f32_16x16x32_bf16(af[m], bfr[n], acc[m][n], 0, 0, 0);
    }
    mbar();                       // all waves done reading buf[t&1]
    if (t + 2 < T) stage(t + 2, t & 1);
  }

#pragma unroll
  for (int m = 0; m < MFR; ++m)
#pragma unroll
    for (int n = 0; n < 4; ++n) {
      const size_t c = col0 + wc + n * 16 + lo;
      const float bv = bias[c];
#pragma unroll
      for (int i = 0; i < 4; ++i) {
        const size_t r = row0 + wr + m * 16 + hi * 4 + i;
        float v = acc[m][n][i] + bv;
        if (RELU) v = fmaxf(v, 0.0f);
        if (WF32) Cf[r * (size_t)N + c] = v;
        if (WB16) Cb[r * (size_t)N + c] = f2b(v);
      }
    }
}

// ---------------- 256x256 8-phase GEMM (FC), 2000 blocks, split-phase nt epilogue ----------------
template<int KC>
__global__ __launch_bounds__(512, 2)
void gemm256(const u16* __restrict__ A, const u16* __restrict__ B,
             const float* __restrict__ bias, float* __restrict__ C,
             int M, int N)
{
  constexpr int T = KC / 64;
  __shared__ __align__(16) u16 LA[2][256 * 64];
  __shared__ __align__(16) u16 LB[2][256 * 64];
  const int tid = threadIdx.x;
  const int wid = tid >> 6, lane = tid & 63;
  const int lo = lane & 15, hi = lane >> 4;
  const int nbn = N >> 8;
  const int cpx = (int)gridDim.x >> 3;
  const int bid = blockIdx.x;
  const int swz = (bid & 7) * cpx + (bid >> 3);
  const int bi = swz / nbn, bj = swz - bi * nbn;
  const size_t row0 = (size_t)bi << 8, col0 = (size_t)bj << 8;
  const int wrow = (wid >> 2) << 7;
  const int wcol = (wid & 3) << 6;

  const int srow = (wid << 3) + (lane >> 3);
  const int scol = ((lane & 7) ^ (lane >> 3)) << 3;
  const u16* srcA = A + (row0 + srow) * (size_t)KC + scol;
  const u16* srcB = B + (col0 + srow) * (size_t)KC + scol;
  const int ldst = wid << 9;

  f32x4 acc[8][4] = {};

  auto stage = [&](int t, int b) {
    const size_t ko = (size_t)t * 64;
#pragma unroll
    for (int i = 0; i < 4; ++i)
      gload16(srcA + ko + (size_t)(i * 64) * KC, &LA[b][ldst + i * 4096]);
#pragma unroll
    for (int i = 0; i < 4; ++i)
      gload16(srcB + ko + (size_t)(i * 64) * KC, &LB[b][ldst + i * 4096]);
  };

  auto rd = [&](const u16* base, int row, int ks) -> bf16x8 {
    const int byte = row * 128 + ((((ks << 2) | hi) ^ (row & 7)) << 4);
    return *(const bf16x8*)((const char*)base + byte);
  };

  auto storeHalf = [&](int mbase) {
#pragma unroll
    for (int m = 0; m < 4; ++m)
#pragma unroll
      for (int n = 0; n < 4; ++n) {
        const size_t c = col0 + wcol + n * 16 + lo;
        const float bv = bias[c];
#pragma unroll
        for (int i = 0; i < 4; ++i) {
          const size_t r = row0 + wrow + (mbase + m) * 16 + hi * 4 + i;
          __builtin_nontemporal_store(acc[mbase + m][n][i] + bv, &C[r * (size_t)N + c]);
        }
      }
  };

  stage(0, 0);
  stage(1, 1);

  for (int t = 0; t < T - 1; ++t) {
    const int b = t & 1;
    const u16* Ab = LA[b];
    const u16* Bb = LB[b];
    asm volatile("s_waitcnt vmcnt(8)" ::: "memory");
    __builtin_amdgcn_sched_barrier(0);
    mbar();

    bf16x8 afr[4], bfr[4];
#pragma unroll
    for (int ks = 0; ks < 2; ++ks) {
#pragma unroll
      for (int m = 0; m < 4; ++m) afr[m] = rd(Ab, wrow + m * 16 + lo, ks);
#pragma unroll
      for (int n = 0; n < 4; ++n) bfr[n] = rd(Bb, wcol + n * 16 + lo, ks);
      mbar();
      asm volatile("s_waitcnt lgkmcnt(0)" ::: "memory");
      __builtin_amdgcn_sched_barrier(0);
      __builtin_amdgcn_s_setprio(1);
#pragma unroll
      for (int m = 0; m < 4; ++m)
#pragma unroll
        for (int n = 0; n < 4; ++n)
          acc[m][n] = __builtin_amdgcn_mfma_f32_16x16x32_bf16(afr[m], bfr[n], acc[m][n], 0, 0, 0);
      __builtin_amdgcn_s_setprio(0);
      mbar();
#pragma unroll
      for (int m = 0; m < 4; ++m) afr[m] = rd(Ab, wrow + (4 + m) * 16 + lo, ks);
      mbar();
      asm volatile("s_waitcnt lgkmcnt(0)" ::: "memory");
      __builtin_amdgcn_sched_barrier(0);
      __builtin_amdgcn_s_setprio(1);
#pragma unroll
      for (int m = 0; m < 4; ++m)
#pragma unroll
        for (int n = 0; n < 4; ++n)
          acc[4 + m][n] = __builtin_amdgcn_mfma_f32_16x16x32_bf16(afr[m], bfr[n], acc[4 + m][n], 0, 0, 0);
      __builtin_amdgcn_s_setprio(0);
      mbar();
    }
    if (t + 2 < T) stage(t + 2, b);
  }

  // peeled last tile with split-phase store issue
  {
    const u16* Ab = LA[(T - 1) & 1];
    const u16* Bb = LB[(T - 1) & 1];
    asm volatile("s_waitcnt vmcnt(0)" ::: "memory");
    __builtin_amdgcn_sched_barrier(0);
    mbar();

    bf16x8 afr[4], bfr[4];
#pragma unroll
    for (int m = 0; m < 4; ++m) afr[m] = rd(Ab, wrow + m * 16 + lo, 0);
#pragma unroll
    for (int n = 0; n < 4; ++n) bfr[n] = rd(Bb, wcol + n * 16 + lo, 0);
    mbar();
    asm volatile("s_waitcnt lgkmcnt(0)" ::: "memory");
    __builtin_amdgcn_sched_barrier(0);
#pragma unroll
    for (int m = 0; m < 4; ++m)
#pragma unroll
      for (int n = 0; n < 4; ++n)
        acc[m][n] = __builtin_amdgcn_mfma_f32_16x16x32_bf16(afr[m], bfr[n], acc[m][n], 0, 0, 0);
    mbar();
#pragma unroll
    for (int m = 0; m < 4; ++m) afr[m] = rd(Ab, wrow + (4 + m) * 16 + lo, 0);
    mbar();
    asm volatile("s_waitcnt lgkmcnt(0)" ::: "memory");
    __builtin_amdgcn_sched_barrier(0);
#pragma unroll
    for (int m = 0; m < 4; ++m)
#pragma unroll
      for (int n = 0; n < 4; ++n)
        acc[4 + m][n] = __builtin_amdgcn_mfma_f32_16x16x32_bf16(afr[m], bfr[n], acc[4 + m][n], 0, 0, 0);
    mbar();
#pragma unroll
    for (int m = 0; m < 4; ++m) afr[m] = rd(Ab, wrow + m * 16 + lo, 1);
#pragma unroll
    for (int n = 0; n < 4; ++n) bfr[n] = rd(Bb, wcol + n * 16 + lo, 1);
    asm volatile("s_waitcnt lgkmcnt(0)" ::: "memory");
    __builtin_amdgcn_sched_barrier(0);
#pragma unroll
    for (int m = 0; m < 4; ++m)
#pragma unroll
      for (int n = 0; n < 4; ++n)
        acc[m][n] = __builtin_amdgcn_mfma_f32_16x16x32_bf16(afr[m], bfr[n], acc[m][n], 0, 0, 0);
    storeHalf(0);
#pragma unroll
    for (int m = 0; m < 4; ++m) afr[m] = rd(Ab, wrow + (4 + m) * 16 + lo, 1);
    asm volatile("s_waitcnt lgkmcnt(0)" ::: "memory");
    __builtin_amdgcn_sched_barrier(0);
#pragma unroll
    for (int m = 0; m < 4; ++m)
#pragma unroll
      for (int n = 0; n < 4; ++n)
        acc[4 + m][n] = __builtin_amdgcn_mfma_f32_16x16x32_bf16(afr[m], bfr[n], acc[4 + m][n], 0, 0, 0);
    storeHalf(4);
  }
}

// ---------------- chunk attention: attend over nc=4 chunks (bf16 qkv) ----------------
__global__ __launch_bounds__(64)
void chunk_attn(const u16* __restrict__ qkv, u16* __restrict__ out) {
  const int p = blockIdx.x, h = blockIdx.y, d = threadIdx.x;
  float q[4], k[4], v[4];
#pragma unroll
  for (int c = 0; c < 4; ++c) {
    const u16* b = qkv + (size_t)((c << 10) + p) * 1536 + (h << 6) + d;
    q[c] = b2f(b[0]); k[c] = b2f(b[512]); v[c] = b2f(b[1024]);
  }
  float sc[4][4];
#pragma unroll
  for (int i = 0; i < 4; ++i)
#pragma unroll
    for (int j = 0; j < 4; ++j) sc[i][j] = q[i] * k[j];
#pragma unroll
  for (int mask = 1; mask < 64; mask <<= 1)
#pragma unroll
    for (int i = 0; i < 4; ++i)
#pragma unroll
      for (int j = 0; j < 4; ++j) sc[i][j] += __shfl_xor(sc[i][j], mask);
#pragma unroll
  for (int i = 0; i < 4; ++i) {
    float s0 = sc[i][0] * 0.125f, s1 = sc[i][1] * 0.125f,
          s2 = sc[i][2] * 0.125f, s3 = sc[i][3] * 0.125f;
    const float mx = fmaxf(fmaxf(s0, s1), fmaxf(s2, s3));
    const float e0 = __expf(s0 - mx), e1 = __expf(s1 - mx),
                e2 = __expf(s2 - mx), e3 = __expf(s3 - mx);
    const float inv = 1.0f / (e0 + e1 + e2 + e3);
    const float o = (e0 * v[0] + e1 * v[1] + e2 * v[2] + e3 * v[3]) * inv;
    out[(size_t)((i << 10) + p) * 512 + (h << 6) + d] = f2b(o);
  }
}

// ---------------- global flash attention: KV-split x2, swapped QK^T ----------------
__global__ __launch_bounds__(512, 4)
void flash_attn(const u16* __restrict__ qkv, float* __restrict__ pO,
                float* __restrict__ pm, float* __restrict__ pl) {
  __shared__ __align__(16) u16 Ks[64 * 64];
  __shared__ __align__(16) u16 Vt[64 * 64];
  __shared__ __align__(16) u16 Pp[8][16 * 64];
  const int tid = threadIdx.x, wid = tid >> 6, lane = tid & 63;
  const int lo = lane & 15, hi = lane >> 4;
  const int q0 = blockIdx.x << 7, h = blockIdx.y, z = blockIdx.z;
  const int kvb = z << 11;
  const int hoff = h << 6;
  char* KsB = (char*)Ks; char* VtB = (char*)Vt;
  char* Pw = (char*)&Pp[wid][0];
  const int xsw = (lo & 7) << 4;
  constexpr float C1 = 0.18033688011112042f;

  bf16x8 qf[2];
#pragma unroll
  for (int kh = 0; kh < 2; ++kh)
    qf[kh] = *(const bf16x8*)(qkv + (size_t)(q0 + wid * 16 + lo) * 1536 + hoff + kh * 32 + hi * 8);

  f32x4 o[4] = {};
  float mr = -3e38f, lr = 0.f;

  const int krow = tid >> 3, kq = tid & 7;

  bf16x8 kpre = *(const bf16x8*)(qkv + (size_t)(kvb + krow) * 1536 + 512 + hoff + kq * 8);
  bf16x8 vpre = *(const bf16x8*)(qkv + (size_t)(kvb + krow) * 1536 + 1024 + hoff + kq * 8);

  for (int kv0 = kvb; kv0 < kvb + 2048; kv0 += 64) {
    __syncthreads();
    *(bf16x8*)(KsB + ((krow * 128 + kq * 16) ^ ((krow & 7) << 4))) = kpre;
    {
      const unsigned* vp = (const unsigned*)&vpre;
      const int oddr = krow & 1;
      const unsigned t0 = oddr ? vp[0] : vp[2];
      const unsigned t1 = oddr ? vp[1] : vp[3];
      const unsigned r0 = (unsigned)__shfl_xor((int)t0, 8);
      const unsigned r1 = (unsigned)__shfl_xor((int)t1, 8);
      const unsigned E0 = oddr ? r0 : vp[0];
      const unsigned E1 = oddr ? r1 : vp[1];
      const unsigned O0 = oddr ? vp[2] : r0;
      const unsigned O1 = oddr ? vp[3] : r1;
      const int jp = krow & ~1;
      const int db = kq * 8 + oddr * 4;
      unsigned w0 = (E0 & 0xffffu) | (O0 << 16);
      unsigned w1 = (E0 >> 16) | (O0 & 0xffff0000u);
      unsigned w2 = (E1 & 0xffffu) | (O1 << 16);
      unsigned w3 = (E1 >> 16) | (O1 & 0xffff0000u);
      *(unsigned*)(VtB + (((db + 0) * 128 + 2 * jp) ^ (((db + 0) & 7) << 4))) = w0;
      *(unsigned*)(VtB + (((db + 1) * 128 + 2 * jp) ^ (((db + 1) & 7) << 4))) = w1;
      *(unsigned*)(VtB + (((db + 2) * 128 + 2 * jp) ^ (((db + 2) & 7) << 4))) = w2;
      *(unsigned*)(VtB + (((db + 3) * 128 + 2 * jp) ^ (((db + 3) & 7) << 4))) = w3;
    }
    __syncthreads();
    if (kv0 + 64 < kvb + 2048) {
      kpre = *(const bf16x8*)(qkv + (size_t)(kv0 + 64 + krow) * 1536 + 512 + hoff + kq * 8);
      vpre = *(const bf16x8*)(qkv + (size_t)(kv0 + 64 + krow) * 1536 + 1024 + hoff + kq * 8);
    }

    f32x4 s[4] = {};
#pragma unroll
    for (int n = 0; n < 4; ++n) {
      const int key = n * 16 + lo;
#pragma unroll
      for (int kh = 0; kh < 2; ++kh) {
        bf16x8 kf = *(const bf16x8*)(KsB + ((key * 128 + kh * 64 + hi * 16) ^ ((key & 7) << 4)));
        s[n] = __builtin_amdgcn_mfma_f32_16x16x32_bf16(kf, qf[kh], s[n], 0, 0, 0);
      }
    }

    float pmx = s[0][0];
#pragma unroll
    for (int n = 0; n < 4; ++n)
#pragma unroll
      for (int i = 0; i < 4; ++i) pmx = fmaxf(pmx, s[n][i]);
    pmx = fmaxf(pmx, __shfl_xor(pmx, 16));
    pmx = fmaxf(pmx, __shfl_xor(pmx, 32));

    if (__any(pmx > mr + 64.f)) {
      const float mn = fmaxf(mr, pmx);
      const float sc = exp2f((mr - mn) * C1);
      mr = mn;
      lr *= sc;
#pragma unroll
      for (int i = 0; i < 4; ++i) {
        const float sq = __shfl(sc, hi * 4 + i);
#pragma unroll
        for (int n = 0; n < 4; ++n) o[n][i] *= sq;
      }
    }

    const float mc = mr * C1;
    float rs = 0.f;
    unsigned U[8];
#pragma unroll
    for (int n = 0; n < 4; ++n) {
      const float p0 = exp2f(fmaf(s[n][0], C1, -mc));
      const float p1 = exp2f(fmaf(s[n][1], C1, -mc));
      const float p2 = exp2f(fmaf(s[n][2], C1, -mc));
      const float p3 = exp2f(fmaf(s[n][3], C1, -mc));
      rs += (p0 + p1) + (p2 + p3);
      asm("v_cvt_pk_bf16_f32 %0, %1, %2" : "=v"(U[2 * n])     : "v"(p0), "v"(p1));
      asm("v_cvt_pk_bf16_f32 %0, %1, %2" : "=v"(U[2 * n + 1]) : "v"(p2), "v"(p3));
    }
    rs += __shfl_xor(rs, 16);
    rs += __shfl_xor(rs, 32);
    lr += rs;
#pragma unroll
    for (int n = 0; n < 4; ++n) {
      const int off = lo * 128 + ((n * 32 + hi * 8) ^ xsw);
      const unsigned long long dw = (unsigned long long)U[2 * n] |
                                    ((unsigned long long)U[2 * n + 1] << 32);
      *(unsigned long long*)(Pw + off) = dw;
    }

#pragma unroll
    for (int kh = 0; kh < 2; ++kh) {
      bf16x8 pa = *(const bf16x8*)(Pw + lo * 128 + ((kh * 64 + hi * 16) ^ xsw));
#pragma unroll
      for (int n = 0; n < 4; ++n) {
        const int vd = n * 16 + lo;
        bf16x8 vf = *(const bf16x8*)(VtB + ((vd * 128 + kh * 64 + hi * 16) ^ ((vd & 7) << 4)));
        o[n] = __builtin_amdgcn_mfma_f32_16x16x32_bf16(pa, vf, o[n], 0, 0, 0);
      }
    }
  }

#pragma unroll
  for (int i = 0; i < 4; ++i) {
    const int r = q0 + wid * 16 + hi * 4 + i;
#pragma unroll
    for (int n = 0; n < 4; ++n)
      pO[((size_t)z * 4096 + r) * 512 + hoff + n * 16 + lo] = o[n][i];
  }
  if (hi == 0) {
    const int r = q0 + wid * 16 + lo;
    pm[(z * 8 + h) * 4096 + r] = mr;
    pl[(z * 8 + h) * 4096 + r] = lr;
  }
}

// ---------------- merge the two KV-half partials ----------------
__global__ __launch_bounds__(256)
void attn_merge(const float* __restrict__ pO, const float* __restrict__ pm,
                const float* __restrict__ pl, u16* __restrict__ out) {
  constexpr float C1 = 0.18033688011112042f;
  const int tid = threadIdx.x, lane = tid & 63, w = tid >> 6;
  const int row = blockIdx.x * 4 + w;
  const int d = lane * 8, h = lane >> 3;
  const float m0 = pm[h * 4096 + row], m1 = pm[(8 + h) * 4096 + row];
  const float l0 = pl[h * 4096 + row], l1 = pl[(8 + h) * 4096 + row];
  const float M = fmaxf(m0, m1);
  const float w0 = exp2f((m0 - M) * C1), w1 = exp2f((m1 - M) * C1);
  const float inv = 1.0f / (l0 * w0 + l1 * w1);
  const float* a = pO + (size_t)row * 512 + d;
  const float* b = pO + ((size_t)4096 + row) * 512 + d;
  float4 a0 = *(const float4*)a, a1 = *(const float4*)(a + 4);
  float4 b0 = *(const float4*)b, b1 = *(const float4*)(b + 4);
  const float A[8] = {a0.x, a0.y, a0.z, a0.w, a1.x, a1.y, a1.z, a1.w};
  const float Bv[8] = {b0.x, b0.y, b0.z, b0.w, b1.x, b1.y, b1.z, b1.w};
#pragma unroll
  for (int j = 0; j < 8; ++j)
    out[(size_t)row * 512 + d + j] = f2b((A[j] * w0 + Bv[j] * w1) * inv);
}

// ---------------- residual add + LayerNorm ----------------
__global__ __launch_bounds__(256)
void add_ln(const float* __restrict__ a, const float* __restrict__ b,
            const float* __restrict__ g, const float* __restrict__ be,
            float* __restrict__ of, u16* __restrict__ ob) {
  const int wid = threadIdx.x >> 6, lane = threadIdx.x & 63;
  const int row = blockIdx.x * 4 + wid;
  const size_t base = (size_t)row * 512 + lane * 8;
  float4 a0 = *(const float4*)(a + base), a1 = *(const float4*)(a + base + 4);
  float4 b0 = *(const float4*)(b + base), b1 = *(const float4*)(b + base + 4);
  float x[8] = {a0.x + b0.x, a0.y + b0.y, a0.z + b0.z, a0.w + b0.w,
                a1.x + b1.x, a1.y + b1.y, a1.z + b1.z, a1.w + b1.w};
  float s = 0.f, sq = 0.f;
#pragma unroll
  for (int j = 0; j < 8; ++j) { s += x[j]; sq += x[j] * x[j]; }
#pragma unroll
  for (int mask = 1; mask < 64; mask <<= 1) {
    s += __shfl_xor(s, mask);
    sq += __shfl_xor(sq, mask);
  }
  const float mean = s * (1.0f / 512.0f);
  const float var = sq * (1.0f / 512.0f) - mean * mean;
  const float rstd = rsqrtf(var + 1e-5f);
  float4 g0 = *(const float4*)(g + lane * 8), g1 = *(const float4*)(g + lane * 8 + 4);
  float4 e0 = *(const float4*)(be + lane * 8), e1 = *(const float4*)(be + lane * 8 + 4);
  const float gg[8] = {g0.x, g0.y, g0.z, g0.w, g1.x, g1.y, g1.z, g1.w};
  const float bb[8] = {e0.x, e0.y, e0.z, e0.w, e1.x, e1.y, e1.z, e1.w};
#pragma unroll
  for (int j = 0; j < 8; ++j) {
    const float y = (x[j] - mean) * rstd * gg[j] + bb[j];
    of[base + j] = y;
    ob[base + j] = f2b(y);
  }
}

extern "C" void kernel_launch(void* const* d_in, const int* in_sizes, int n_in,
                              void* d_out, int out_size, void* d_ws, size_t ws_size,
                              hipStream_t stream) {
  (void)in_sizes; (void)n_in; (void)out_size; (void)ws_size;
  const int*   tokens = (const int*)d_in[0];
  const float* emb    = (const float*)d_in[1];
  const float* cwin   = (const float*)d_in[2];
  const float* cbin   = (const float*)d_in[3];
  const float* cwout  = (const float*)d_in[4];
  const float* cbout  = (const float*)d_in[5];
  const float* gwin   = (const float*)d_in[6];
  const float* gbin   = (const float*)d_in[7];
  const float* gwout  = (const float*)d_in[8];
  const float* gbout  = (const float*)d_in[9];
  const float* ln1g   = (const float*)d_in[10];
  const float* ln1b   = (const float*)d_in[11];
  const float* fw1    = (const float*)d_in[12];
  const float* fb1    = (const float*)d_in[13];
  const float* fw2    = (const float*)d_in[14];
  const float* fb2    = (const float*)d_in[15];
  const float* ln2g   = (const float*)d_in[16];
  const float* ln2b   = (const float*)d_in[17];
  const float* fcw    = (const float*)d_in[18];
  const float* fcb    = (const float*)d_in[19];
  float* out = (float*)d_out;

  char* ws = (char*)d_ws;
  size_t off = 0;
  auto alloc = [&](size_t bytes) -> void* {
    void* p = ws + off;
    off += (bytes + 255) & ~(size_t)255;
    return p;
  };
  u16*   xb    = (u16*)alloc((size_t)4096 * 512 * 2);
  float* xf    = (float*)alloc((size_t)4096 * 512 * 4);
  u16*   qkv1b = (u16*)alloc((size_t)4096 * 1536 * 2);   // + at1 reused as pO
  u16*   at1   = (u16*)alloc((size_t)4096 * 512 * 2);
  u16*   cab   = (u16*)alloc((size_t)4096 * 512 * 2);
  u16*   qkv2  = (u16*)alloc((size_t)4096 * 1536 * 2);
  u16*   at2   = (u16*)alloc((size_t)4096 * 512 * 2);
  float* gaf   = (float*)alloc((size_t)4096 * 512 * 4);
  float* x1f   = (float*)alloc((size_t)4096 * 512 * 4);
  u16*   x1b   = (u16*)alloc((size_t)4096 * 512 * 2);
  u16*   f1b   = (u16*)alloc((size_t)4096 * 2048 * 2);
  float* ff    = (float*)alloc((size_t)4096 * 512 * 4);
  float* x2f   = (float*)alloc((size_t)4096 * 512 * 4);
  u16*   x2b   = (u16*)alloc((size_t)4096 * 512 * 2);
  u16*   wcinb  = (u16*)alloc((size_t)1536 * 512 * 2);
  u16*   wcoutb = (u16*)alloc((size_t)512 * 512 * 2);
  u16*   wginb  = (u16*)alloc((size_t)1536 * 512 * 2);
  u16*   wgoutb = (u16*)alloc((size_t)512 * 512 * 2);
  u16*   wf1b   = (u16*)alloc((size_t)2048 * 512 * 2);
  u16*   wf2b   = (u16*)alloc((size_t)512 * 2048 * 2);
  u16*   wfcb   = (u16*)alloc((size_t)32000 * 512 * 2);

  // temporal aliases (dead by the global-attention stage)
  float* pO = (float*)qkv1b;       // 2 x 4096 x 512 f32 = 16 MB (qkv1b 12MB + at1 4MB)
  float* pm = (float*)xb;          // 2 x 8 x 4096 f32
  float* pl = pm + 2 * 8 * 4096;

  // fused embed+PE | weight conversion
  prep<<<4096 + 2048, 256, 0, stream>>>(
      tokens, emb, xf, xb,
      (const float4*)cwin, wcinb, (const float4*)cwout, wcoutb,
      (const float4*)gwin, wginb, (const float4*)gwout, wgoutb,
      (const float4*)fw1, wf1b, (const float4*)fw2, wf2b,
      (const float4*)fcw, wfcb);

  // chunk stage
  gemm_bt<64, 0, 0, 1><<<768, 256, 0, stream>>>(xb, wcinb, cbin, (float*)nullptr, qkv1b, 4096, 1536, 512);
  chunk_attn<<<dim3(1024, 8), 64, 0, stream>>>(qkv1b, at1);
  gemm_bt<64, 0, 0, 1><<<256, 256, 0, stream>>>(at1, wcoutb, cbout, (float*)nullptr, cab, 4096, 512, 512);

  // global stage
  gemm_bt<64, 0, 0, 1><<<768, 256, 0, stream>>>(cab, wginb, gbin, (float*)nullptr, qkv2, 4096, 1536, 512);
  flash_attn<<<dim3(32, 8, 2), 512, 0, stream>>>(qkv2, pO, pm, pl);
  attn_merge<<<1024, 256, 0, stream>>>(pO, pm, pl, at2);
  gemm_bt<64, 0, 1, 0><<<256, 256, 0, stream>>>(at2, wgoutb, gbout, gaf, (u16*)nullptr, 4096, 512, 512);

  // post-norm encoder layer
  add_ln<<<1024, 256, 0, stream>>>(xf, gaf, ln1g, ln1b, x1f, x1b);
  gemm_bt<64, 1, 0, 1><<<1024, 256, 0, stream>>>(x1b, wf1b, fb1, (float*)nullptr, f1b, 4096, 2048, 512);
  gemm_bt<64, 0, 1, 0><<<256, 256, 0, stream>>>(f1b, wf2b, fb2, ff, (u16*)nullptr, 4096, 512, 2048);
  add_ln<<<1024, 256, 0, stream>>>(x1f, ff, ln2g, ln2b, x2f, x2b);

  // vocab projection: 2000-block 256^2 pipeline, split-phase nt epilogue
  gemm256<512><<<2000, 512, 0, stream>>>(x2b, wfcb, fcb, out, 4096, 32000);
}

// Round 10
// 426.629 us; speedup vs baseline: 1.1786x; 1.0243x over previous
//
#include <hip/hip_runtime.h>

typedef __attribute__((ext_vector_type(8))) short bf16x8;
typedef __attribute__((ext_vector_type(4))) float f32x4;
typedef unsigned short u16;

__device__ __forceinline__ u16 f2b(float f) {
  union { float f; unsigned u; } v; v.f = f;
  return (u16)((v.u + 0x7FFFu + ((v.u >> 16) & 1u)) >> 16);
}
__device__ __forceinline__ float b2f(u16 x) {
  union { unsigned u; float f; } v; v.u = (unsigned)x << 16; return v.f;
}

__device__ __forceinline__ void gload16(const void* g, void* l) {
  __builtin_amdgcn_global_load_lds((__attribute__((address_space(1))) void*)(g),
                                   (__attribute__((address_space(3))) void*)(l),
                                   16, 0, 0);
}

__device__ __forceinline__ void mbar() {
  asm volatile("" ::: "memory");
  __builtin_amdgcn_s_barrier();
  asm volatile("" ::: "memory");
}

// ---------------- fused prep: embedding+PE (blocks 0..4095) | weight f2b (rest) ----------------
__device__ __forceinline__ void cv1(const float4* __restrict__ s, u16* __restrict__ d, int i) {
  float4 v = s[i];
  unsigned long long pk = (unsigned long long)f2b(v.x) |
                          ((unsigned long long)f2b(v.y) << 16) |
                          ((unsigned long long)f2b(v.z) << 32) |
                          ((unsigned long long)f2b(v.w) << 48);
  *(unsigned long long*)(d + (size_t)i * 4) = pk;
}

__global__ __launch_bounds__(256)
void prep(const int* __restrict__ tok, const float* __restrict__ emb,
          float* __restrict__ xf, u16* __restrict__ xb,
          const float4* s0, u16* d0, const float4* s1, u16* d1,
          const float4* s2, u16* d2, const float4* s3, u16* d3,
          const float4* s4, u16* d4, const float4* s5, u16* d5,
          const float4* s6, u16* d6) {
  if (blockIdx.x < 4096) {
    const int s = blockIdx.x;
    const int i = threadIdx.x;
    const int t = tok[s];
    const float div = __expf((float)(2 * i) * -0.017988946039015984f);
    const float ang = (float)s * div;
    const float sv = __sinf(ang), cv = __cosf(ang);
    const float* e = emb + (size_t)t * 512 + 2 * i;
    const float x0 = e[0] * 22.627416997969522f + sv;
    const float x1 = e[1] * 22.627416997969522f + cv;
    const size_t o = (size_t)s * 512 + 2 * i;
    xf[o] = x0; xf[o + 1] = x1;
    xb[o] = f2b(x0); xb[o + 1] = f2b(x1);
    return;
  }
  int i = (blockIdx.x - 4096) * 256 + threadIdx.x;
  const int stride = ((int)gridDim.x - 4096) * 256;
  for (; i < 5144576; i += stride) {
    int j = i;
    if (j < 196608) { cv1(s0, d0, j); continue; }
    j -= 196608;
    if (j < 65536) { cv1(s1, d1, j); continue; }
    j -= 65536;
    if (j < 196608) { cv1(s2, d2, j); continue; }
    j -= 196608;
    if (j < 65536) { cv1(s3, d3, j); continue; }
    j -= 65536;
    if (j < 262144) { cv1(s4, d4, j); continue; }
    j -= 262144;
    if (j < 262144) { cv1(s5, d5, j); continue; }
    j -= 262144;
    cv1(s6, d6, j);
  }
}

// ---- tiled GEMM, counted-vmcnt double-buffer; BM x BN tile, 4 waves ----
// C = A(MxK,bf16) . B(NxK,bf16)^T + bias
template<int BM, int BN, int RELU, int WF32, int WB16>
__global__ __launch_bounds__(256)
void gemm_bt(const u16* __restrict__ A, const u16* __restrict__ B,
             const float* __restrict__ bias, float* __restrict__ Cf,
             u16* __restrict__ Cb, int M, int N, int K)
{
  constexpr int MFR = BM / 32;          // m-frags per wave
  constexpr int NFR = BN / 32;          // n-frags per wave
  constexpr int INFLT = BM / 32 + BN / 32;  // gloads per stage
  __shared__ __align__(16) u16 As[2][BM * 64];
  __shared__ __align__(16) u16 Bs[2][BN * 64];
  const int tid = threadIdx.x;
  const int wid = tid >> 6, lane = tid & 63;
  const int lo = lane & 15, hi = lane >> 4;
  const int nbn = N / BN;
  const int cpx = (int)gridDim.x >> 3;
  const int bid = blockIdx.x;
  const int swz = (bid & 7) * cpx + (bid >> 3);
  const int bi = swz / nbn, bj = swz - bi * nbn;
  const size_t row0 = (size_t)bi * BM, col0 = (size_t)bj * BN;
  const int wr = (wid >> 1) * (BM / 2), wc = (wid & 1) * (BN / 2);
  const int srow = (wid << 3) + (lane >> 3);
  const int scol = ((lane & 7) ^ (lane >> 3)) << 3;

  f32x4 acc[MFR][NFR] = {};

  auto stage = [&](int t, int b) {
    const int k0 = t << 6;
#pragma unroll
    for (int p = 0; p < BM / 32; ++p)
      gload16(A + (row0 + srow + 32 * p) * (size_t)K + k0 + scol, &As[b][(wid * 8 + 32 * p) * 64]);
#pragma unroll
    for (int p = 0; p < BN / 32; ++p)
      gload16(B + (col0 + srow + 32 * p) * (size_t)K + k0 + scol, &Bs[b][(wid * 8 + 32 * p) * 64]);
  };

  auto rdf = [&](const u16* base, int row, int ks) -> bf16x8 {
    return *(const bf16x8*)((const char*)base + row * 128 + ((((ks << 2) | hi) ^ (row & 7)) << 4));
  };

  const int T = K >> 6;
  stage(0, 0);
  stage(1, 1);

  for (int t = 0; t < T; ++t) {
    if (t + 1 < T) {
      if constexpr (INFLT == 4)      { asm volatile("s_waitcnt vmcnt(4)" ::: "memory"); }
      else if constexpr (INFLT == 6) { asm volatile("s_waitcnt vmcnt(6)" ::: "memory"); }
      else                           { asm volatile("s_waitcnt vmcnt(8)" ::: "memory"); }
    } else {
      asm volatile("s_waitcnt vmcnt(0)" ::: "memory");
    }
    __builtin_amdgcn_sched_barrier(0);
    mbar();                       // tile t visible to all waves
    const u16* Ab = As[t & 1];
    const u16* Bb = Bs[t & 1];
#pragma unroll
    for (int ks = 0; ks < 2; ++ks) {
      bf16x8 af[MFR], bfr[NFR];
#pragma unroll
      for (int m = 0; m < MFR; ++m) af[m] = rdf(Ab, wr + m * 16 + lo, ks);
#pragma unroll
      for (int n = 0; n < NFR; ++n) bfr[n] = rdf(Bb, wc + n * 16 + lo, ks);
#pragma unroll
      for (int m = 0; m < MFR; ++m)
#pragma unroll
        for (int n = 0; n < NFR; ++n)
          acc[m][n] = __builtin_amdgcn_mfma_f32_16x16x32_bf16(af[m], bfr[n], acc[m][n], 0, 0, 0);
    }
    mbar();                       // all waves done reading buf[t&1]
    if (t + 2 < T) stage(t + 2, t & 1);
  }

#pragma unroll
  for (int m = 0; m < MFR; ++m)
#pragma unroll
    for (int n = 0; n < NFR; ++n) {
      const size_t c = col0 + wc + n * 16 + lo;
      const float bv = bias[c];
#pragma unroll
      for (int i = 0; i < 4; ++i) {
        const size_t r = row0 + wr + m * 16 + hi * 4 + i;
        float v = acc[m][n][i] + bv;
        if (RELU) v = fmaxf(v, 0.0f);
        if (WF32) Cf[r * (size_t)N + c] = v;
        if (WB16) Cb[r * (size_t)N + c] = f2b(v);
      }
    }
}

// ---------------- 256x256 8-phase GEMM (FC), 2000 blocks, split-phase nt epilogue ----------------
template<int KC>
__global__ __launch_bounds__(512, 2)
void gemm256(const u16* __restrict__ A, const u16* __restrict__ B,
             const float* __restrict__ bias, float* __restrict__ C,
             int M, int N)
{
  constexpr int T = KC / 64;
  __shared__ __align__(16) u16 LA[2][256 * 64];
  __shared__ __align__(16) u16 LB[2][256 * 64];
  const int tid = threadIdx.x;
  const int wid = tid >> 6, lane = tid & 63;
  const int lo = lane & 15, hi = lane >> 4;
  const int nbn = N >> 8;
  const int cpx = (int)gridDim.x >> 3;
  const int bid = blockIdx.x;
  const int swz = (bid & 7) * cpx + (bid >> 3);
  const int bi = swz / nbn, bj = swz - bi * nbn;
  const size_t row0 = (size_t)bi << 8, col0 = (size_t)bj << 8;
  const int wrow = (wid >> 2) << 7;
  const int wcol = (wid & 3) << 6;

  const int srow = (wid << 3) + (lane >> 3);
  const int scol = ((lane & 7) ^ (lane >> 3)) << 3;
  const u16* srcA = A + (row0 + srow) * (size_t)KC + scol;
  const u16* srcB = B + (col0 + srow) * (size_t)KC + scol;
  const int ldst = wid << 9;

  f32x4 acc[8][4] = {};

  auto stage = [&](int t, int b) {
    const size_t ko = (size_t)t * 64;
#pragma unroll
    for (int i = 0; i < 4; ++i)
      gload16(srcA + ko + (size_t)(i * 64) * KC, &LA[b][ldst + i * 4096]);
#pragma unroll
    for (int i = 0; i < 4; ++i)
      gload16(srcB + ko + (size_t)(i * 64) * KC, &LB[b][ldst + i * 4096]);
  };

  auto rd = [&](const u16* base, int row, int ks) -> bf16x8 {
    const int byte = row * 128 + ((((ks << 2) | hi) ^ (row & 7)) << 4);
    return *(const bf16x8*)((const char*)base + byte);
  };

  auto storeHalf = [&](int mbase) {
#pragma unroll
    for (int m = 0; m < 4; ++m)
#pragma unroll
      for (int n = 0; n < 4; ++n) {
        const size_t c = col0 + wcol + n * 16 + lo;
        const float bv = bias[c];
#pragma unroll
        for (int i = 0; i < 4; ++i) {
          const size_t r = row0 + wrow + (mbase + m) * 16 + hi * 4 + i;
          __builtin_nontemporal_store(acc[mbase + m][n][i] + bv, &C[r * (size_t)N + c]);
        }
      }
  };

  stage(0, 0);
  stage(1, 1);

  for (int t = 0; t < T - 1; ++t) {
    const int b = t & 1;
    const u16* Ab = LA[b];
    const u16* Bb = LB[b];
    asm volatile("s_waitcnt vmcnt(8)" ::: "memory");
    __builtin_amdgcn_sched_barrier(0);
    mbar();

    bf16x8 afr[4], bfr[4];
#pragma unroll
    for (int ks = 0; ks < 2; ++ks) {
#pragma unroll
      for (int m = 0; m < 4; ++m) afr[m] = rd(Ab, wrow + m * 16 + lo, ks);
#pragma unroll
      for (int n = 0; n < 4; ++n) bfr[n] = rd(Bb, wcol + n * 16 + lo, ks);
      mbar();
      asm volatile("s_waitcnt lgkmcnt(0)" ::: "memory");
      __builtin_amdgcn_sched_barrier(0);
      __builtin_amdgcn_s_setprio(1);
#pragma unroll
      for (int m = 0; m < 4; ++m)
#pragma unroll
        for (int n = 0; n < 4; ++n)
          acc[m][n] = __builtin_amdgcn_mfma_f32_16x16x32_bf16(afr[m], bfr[n], acc[m][n], 0, 0, 0);
      __builtin_amdgcn_s_setprio(0);
      mbar();
#pragma unroll
      for (int m = 0; m < 4; ++m) afr[m] = rd(Ab, wrow + (4 + m) * 16 + lo, ks);
      mbar();
      asm volatile("s_waitcnt lgkmcnt(0)" ::: "memory");
      __builtin_amdgcn_sched_barrier(0);
      __builtin_amdgcn_s_setprio(1);
#pragma unroll
      for (int m = 0; m < 4; ++m)
#pragma unroll
        for (int n = 0; n < 4; ++n)
          acc[4 + m][n] = __builtin_amdgcn_mfma_f32_16x16x32_bf16(afr[m], bfr[n], acc[4 + m][n], 0, 0, 0);
      __builtin_amdgcn_s_setprio(0);
      mbar();
    }
    if (t + 2 < T) stage(t + 2, b);
  }

  // peeled last tile with split-phase store issue
  {
    const u16* Ab = LA[(T - 1) & 1];
    const u16* Bb = LB[(T - 1) & 1];
    asm volatile("s_waitcnt vmcnt(0)" ::: "memory");
    __builtin_amdgcn_sched_barrier(0);
    mbar();

    bf16x8 afr[4], bfr[4];
#pragma unroll
    for (int m = 0; m < 4; ++m) afr[m] = rd(Ab, wrow + m * 16 + lo, 0);
#pragma unroll
    for (int n = 0; n < 4; ++n) bfr[n] = rd(Bb, wcol + n * 16 + lo, 0);
    mbar();
    asm volatile("s_waitcnt lgkmcnt(0)" ::: "memory");
    __builtin_amdgcn_sched_barrier(0);
#pragma unroll
    for (int m = 0; m < 4; ++m)
#pragma unroll
      for (int n = 0; n < 4; ++n)
        acc[m][n] = __builtin_amdgcn_mfma_f32_16x16x32_bf16(afr[m], bfr[n], acc[m][n], 0, 0, 0);
    mbar();
#pragma unroll
    for (int m = 0; m < 4; ++m) afr[m] = rd(Ab, wrow + (4 + m) * 16 + lo, 0);
    mbar();
    asm volatile("s_waitcnt lgkmcnt(0)" ::: "memory");
    __builtin_amdgcn_sched_barrier(0);
#pragma unroll
    for (int m = 0; m < 4; ++m)
#pragma unroll
      for (int n = 0; n < 4; ++n)
        acc[4 + m][n] = __builtin_amdgcn_mfma_f32_16x16x32_bf16(afr[m], bfr[n], acc[4 + m][n], 0, 0, 0);
    mbar();
#pragma unroll
    for (int m = 0; m < 4; ++m) afr[m] = rd(Ab, wrow + m * 16 + lo, 1);
#pragma unroll
    for (int n = 0; n < 4; ++n) bfr[n] = rd(Bb, wcol + n * 16 + lo, 1);
    asm volatile("s_waitcnt lgkmcnt(0)" ::: "memory");
    __builtin_amdgcn_sched_barrier(0);
#pragma unroll
    for (int m = 0; m < 4; ++m)
#pragma unroll
      for (int n = 0; n < 4; ++n)
        acc[m][n] = __builtin_amdgcn_mfma_f32_16x16x32_bf16(afr[m], bfr[n], acc[m][n], 0, 0, 0);
    storeHalf(0);
#pragma unroll
    for (int m = 0; m < 4; ++m) afr[m] = rd(Ab, wrow + (4 + m) * 16 + lo, 1);
    asm volatile("s_waitcnt lgkmcnt(0)" ::: "memory");
    __builtin_amdgcn_sched_barrier(0);
#pragma unroll
    for (int m = 0; m < 4; ++m)
#pragma unroll
      for (int n = 0; n < 4; ++n)
        acc[4 + m][n] = __builtin_amdgcn_mfma_f32_16x16x32_bf16(afr[m], bfr[n], acc[4 + m][n], 0, 0, 0);
    storeHalf(4);
  }
}

// ---------------- chunk attention: 256 threads, 4 (p,h) pairs per block ----------------
__global__ __launch_bounds__(256)
void chunk_attn(const u16* __restrict__ qkv, u16* __restrict__ out) {
  const int widx = threadIdx.x >> 6, d = threadIdx.x & 63;
  const int g = blockIdx.x * 4 + widx;        // 0..8191
  const int p = g & 1023, h = g >> 10;
  float q[4], k[4], v[4];
#pragma unroll
  for (int c = 0; c < 4; ++c) {
    const u16* b = qkv + (size_t)((c << 10) + p) * 1536 + (h << 6) + d;
    q[c] = b2f(b[0]); k[c] = b2f(b[512]); v[c] = b2f(b[1024]);
  }
  float sc[4][4];
#pragma unroll
  for (int i = 0; i < 4; ++i)
#pragma unroll
    for (int j = 0; j < 4; ++j) sc[i][j] = q[i] * k[j];
#pragma unroll
  for (int mask = 1; mask < 64; mask <<= 1)
#pragma unroll
    for (int i = 0; i < 4; ++i)
#pragma unroll
      for (int j = 0; j < 4; ++j) sc[i][j] += __shfl_xor(sc[i][j], mask);
#pragma unroll
  for (int i = 0; i < 4; ++i) {
    float s0 = sc[i][0] * 0.125f, s1 = sc[i][1] * 0.125f,
          s2 = sc[i][2] * 0.125f, s3 = sc[i][3] * 0.125f;
    const float mx = fmaxf(fmaxf(s0, s1), fmaxf(s2, s3));
    const float e0 = __expf(s0 - mx), e1 = __expf(s1 - mx),
                e2 = __expf(s2 - mx), e3 = __expf(s3 - mx);
    const float inv = 1.0f / (e0 + e1 + e2 + e3);
    const float o = (e0 * v[0] + e1 * v[1] + e2 * v[2] + e3 * v[3]) * inv;
    out[(size_t)((i << 10) + p) * 512 + (h << 6) + d] = f2b(o);
  }
}

// ---------------- global flash attention: KV-split x2, swapped QK^T ----------------
__global__ __launch_bounds__(512, 4)
void flash_attn(const u16* __restrict__ qkv, float* __restrict__ pO,
                float* __restrict__ pm, float* __restrict__ pl) {
  __shared__ __align__(16) u16 Ks[64 * 64];
  __shared__ __align__(16) u16 Vt[64 * 64];
  __shared__ __align__(16) u16 Pp[8][16 * 64];
  const int tid = threadIdx.x, wid = tid >> 6, lane = tid & 63;
  const int lo = lane & 15, hi = lane >> 4;
  const int q0 = blockIdx.x << 7, h = blockIdx.y, z = blockIdx.z;
  const int kvb = z << 11;
  const int hoff = h << 6;
  char* KsB = (char*)Ks; char* VtB = (char*)Vt;
  char* Pw = (char*)&Pp[wid][0];
  const int xsw = (lo & 7) << 4;
  constexpr float C1 = 0.18033688011112042f;

  bf16x8 qf[2];
#pragma unroll
  for (int kh = 0; kh < 2; ++kh)
    qf[kh] = *(const bf16x8*)(qkv + (size_t)(q0 + wid * 16 + lo) * 1536 + hoff + kh * 32 + hi * 8);

  f32x4 o[4] = {};
  float mr = -3e38f, lr = 0.f;

  const int krow = tid >> 3, kq = tid & 7;

  bf16x8 kpre = *(const bf16x8*)(qkv + (size_t)(kvb + krow) * 1536 + 512 + hoff + kq * 8);
  bf16x8 vpre = *(const bf16x8*)(qkv + (size_t)(kvb + krow) * 1536 + 1024 + hoff + kq * 8);

  for (int kv0 = kvb; kv0 < kvb + 2048; kv0 += 64) {
    __syncthreads();
    *(bf16x8*)(KsB + ((krow * 128 + kq * 16) ^ ((krow & 7) << 4))) = kpre;
    {
      const unsigned* vp = (const unsigned*)&vpre;
      const int oddr = krow & 1;
      const unsigned t0 = oddr ? vp[0] : vp[2];
      const unsigned t1 = oddr ? vp[1] : vp[3];
      const unsigned r0 = (unsigned)__shfl_xor((int)t0, 8);
      const unsigned r1 = (unsigned)__shfl_xor((int)t1, 8);
      const unsigned E0 = oddr ? r0 : vp[0];
      const unsigned E1 = oddr ? r1 : vp[1];
      const unsigned O0 = oddr ? vp[2] : r0;
      const unsigned O1 = oddr ? vp[3] : r1;
      const int jp = krow & ~1;
      const int db = kq * 8 + oddr * 4;
      unsigned w0 = (E0 & 0xffffu) | (O0 << 16);
      unsigned w1 = (E0 >> 16) | (O0 & 0xffff0000u);
      unsigned w2 = (E1 & 0xffffu) | (O1 << 16);
      unsigned w3 = (E1 >> 16) | (O1 & 0xffff0000u);
      *(unsigned*)(VtB + (((db + 0) * 128 + 2 * jp) ^ (((db + 0) & 7) << 4))) = w0;
      *(unsigned*)(VtB + (((db + 1) * 128 + 2 * jp) ^ (((db + 1) & 7) << 4))) = w1;
      *(unsigned*)(VtB + (((db + 2) * 128 + 2 * jp) ^ (((db + 2) & 7) << 4))) = w2;
      *(unsigned*)(VtB + (((db + 3) * 128 + 2 * jp) ^ (((db + 3) & 7) << 4))) = w3;
    }
    __syncthreads();
    if (kv0 + 64 < kvb + 2048) {
      kpre = *(const bf16x8*)(qkv + (size_t)(kv0 + 64 + krow) * 1536 + 512 + hoff + kq * 8);
      vpre = *(const bf16x8*)(qkv + (size_t)(kv0 + 64 + krow) * 1536 + 1024 + hoff + kq * 8);
    }

    f32x4 s[4] = {};
#pragma unroll
    for (int n = 0; n < 4; ++n) {
      const int key = n * 16 + lo;
#pragma unroll
      for (int kh = 0; kh < 2; ++kh) {
        bf16x8 kf = *(const bf16x8*)(KsB + ((key * 128 + kh * 64 + hi * 16) ^ ((key & 7) << 4)));
        s[n] = __builtin_amdgcn_mfma_f32_16x16x32_bf16(kf, qf[kh], s[n], 0, 0, 0);
      }
    }

    float pmx = s[0][0];
#pragma unroll
    for (int n = 0; n < 4; ++n)
#pragma unroll
      for (int i = 0; i < 4; ++i) pmx = fmaxf(pmx, s[n][i]);
    pmx = fmaxf(pmx, __shfl_xor(pmx, 16));
    pmx = fmaxf(pmx, __shfl_xor(pmx, 32));

    if (__any(pmx > mr + 64.f)) {
      const float mn = fmaxf(mr, pmx);
      const float sc = exp2f((mr - mn) * C1);
      mr = mn;
      lr *= sc;
#pragma unroll
      for (int i = 0; i < 4; ++i) {
        const float sq = __shfl(sc, hi * 4 + i);
#pragma unroll
        for (int n = 0; n < 4; ++n) o[n][i] *= sq;
      }
    }

    const float mc = mr * C1;
    float rs = 0.f;
    unsigned U[8];
#pragma unroll
    for (int n = 0; n < 4; ++n) {
      const float p0 = exp2f(fmaf(s[n][0], C1, -mc));
      const float p1 = exp2f(fmaf(s[n][1], C1, -mc));
      const float p2 = exp2f(fmaf(s[n][2], C1, -mc));
      const float p3 = exp2f(fmaf(s[n][3], C1, -mc));
      rs += (p0 + p1) + (p2 + p3);
      asm("v_cvt_pk_bf16_f32 %0, %1, %2" : "=v"(U[2 * n])     : "v"(p0), "v"(p1));
      asm("v_cvt_pk_bf16_f32 %0, %1, %2" : "=v"(U[2 * n + 1]) : "v"(p2), "v"(p3));
    }
    rs += __shfl_xor(rs, 16);
    rs += __shfl_xor(rs, 32);
    lr += rs;
#pragma unroll
    for (int n = 0; n < 4; ++n) {
      const int off = lo * 128 + ((n * 32 + hi * 8) ^ xsw);
      const unsigned long long dw = (unsigned long long)U[2 * n] |
                                    ((unsigned long long)U[2 * n + 1] << 32);
      *(unsigned long long*)(Pw + off) = dw;
    }

#pragma unroll
    for (int kh = 0; kh < 2; ++kh) {
      bf16x8 pa = *(const bf16x8*)(Pw + lo * 128 + ((kh * 64 + hi * 16) ^ xsw));
#pragma unroll
      for (int n = 0; n < 4; ++n) {
        const int vd = n * 16 + lo;
        bf16x8 vf = *(const bf16x8*)(VtB + ((vd * 128 + kh * 64 + hi * 16) ^ ((vd & 7) << 4)));
        o[n] = __builtin_amdgcn_mfma_f32_16x16x32_bf16(pa, vf, o[n], 0, 0, 0);
      }
    }
  }

#pragma unroll
  for (int i = 0; i < 4; ++i) {
    const int r = q0 + wid * 16 + hi * 4 + i;
#pragma unroll
    for (int n = 0; n < 4; ++n)
      pO[((size_t)z * 4096 + r) * 512 + hoff + n * 16 + lo] = o[n][i];
  }
  if (hi == 0) {
    const int r = q0 + wid * 16 + lo;
    pm[(z * 8 + h) * 4096 + r] = mr;
    pl[(z * 8 + h) * 4096 + r] = lr;
  }
}

// ---------------- merge the two KV-half partials ----------------
__global__ __launch_bounds__(256)
void attn_merge(const float* __restrict__ pO, const float* __restrict__ pm,
                const float* __restrict__ pl, u16* __restrict__ out) {
  constexpr float C1 = 0.18033688011112042f;
  const int tid = threadIdx.x, lane = tid & 63, w = tid >> 6;
  const int row = blockIdx.x * 4 + w;
  const int d = lane * 8, h = lane >> 3;
  const float m0 = pm[h * 4096 + row], m1 = pm[(8 + h) * 4096 + row];
  const float l0 = pl[h * 4096 + row], l1 = pl[(8 + h) * 4096 + row];
  const float M = fmaxf(m0, m1);
  const float w0 = exp2f((m0 - M) * C1), w1 = exp2f((m1 - M) * C1);
  const float inv = 1.0f / (l0 * w0 + l1 * w1);
  const float* a = pO + (size_t)row * 512 + d;
  const float* b = pO + ((size_t)4096 + row) * 512 + d;
  float4 a0 = *(const float4*)a, a1 = *(const float4*)(a + 4);
  float4 b0 = *(const float4*)b, b1 = *(const float4*)(b + 4);
  const float A[8] = {a0.x, a0.y, a0.z, a0.w, a1.x, a1.y, a1.z, a1.w};
  const float Bv[8] = {b0.x, b0.y, b0.z, b0.w, b1.x, b1.y, b1.z, b1.w};
#pragma unroll
  for (int j = 0; j < 8; ++j)
    out[(size_t)row * 512 + d + j] = f2b((A[j] * w0 + Bv[j] * w1) * inv);
}

// ---------------- residual add + LayerNorm ----------------
template<int WF32>
__global__ __launch_bounds__(256)
void add_ln(const float* __restrict__ a, const float* __restrict__ b,
            const float* __restrict__ g, const float* __restrict__ be,
            float* __restrict__ of, u16* __restrict__ ob) {
  const int wid = threadIdx.x >> 6, lane = threadIdx.x & 63;
  const int row = blockIdx.x * 4 + wid;
  const size_t base = (size_t)row * 512 + lane * 8;
  float4 a0 = *(const float4*)(a + base), a1 = *(const float4*)(a + base + 4);
  float4 b0 = *(const float4*)(b + base), b1 = *(const float4*)(b + base + 4);
  float x[8] = {a0.x + b0.x, a0.y + b0.y, a0.z + b0.z, a0.w + b0.w,
                a1.x + b1.x, a1.y + b1.y, a1.z + b1.z, a1.w + b1.w};
  float s = 0.f, sq = 0.f;
#pragma unroll
  for (int j = 0; j < 8; ++j) { s += x[j]; sq += x[j] * x[j]; }
#pragma unroll
  for (int mask = 1; mask < 64; mask <<= 1) {
    s += __shfl_xor(s, mask);
    sq += __shfl_xor(sq, mask);
  }
  const float mean = s * (1.0f / 512.0f);
  const float var = sq * (1.0f / 512.0f) - mean * mean;
  const float rstd = rsqrtf(var + 1e-5f);
  float4 g0 = *(const float4*)(g + lane * 8), g1 = *(const float4*)(g + lane * 8 + 4);
  float4 e0 = *(const float4*)(be + lane * 8), e1 = *(const float4*)(be + lane * 8 + 4);
  const float gg[8] = {g0.x, g0.y, g0.z, g0.w, g1.x, g1.y, g1.z, g1.w};
  const float bb[8] = {e0.x, e0.y, e0.z, e0.w, e1.x, e1.y, e1.z, e1.w};
#pragma unroll
  for (int j = 0; j < 8; ++j) {
    const float y = (x[j] - mean) * rstd * gg[j] + bb[j];
    if (WF32) of[base + j] = y;
    ob[base + j] = f2b(y);
  }
}

extern "C" void kernel_launch(void* const* d_in, const int* in_sizes, int n_in,
                              void* d_out, int out_size, void* d_ws, size_t ws_size,
                              hipStream_t stream) {
  (void)in_sizes; (void)n_in; (void)out_size; (void)ws_size;
  const int*   tokens = (const int*)d_in[0];
  const float* emb    = (const float*)d_in[1];
  const float* cwin   = (const float*)d_in[2];
  const float* cbin   = (const float*)d_in[3];
  const float* cwout  = (const float*)d_in[4];
  const float* cbout  = (const float*)d_in[5];
  const float* gwin   = (const float*)d_in[6];
  const float* gbin   = (const float*)d_in[7];
  const float* gwout  = (const float*)d_in[8];
  const float* gbout  = (const float*)d_in[9];
  const float* ln1g   = (const float*)d_in[10];
  const float* ln1b   = (const float*)d_in[11];
  const float* fw1    = (const float*)d_in[12];
  const float* fb1    = (const float*)d_in[13];
  const float* fw2    = (const float*)d_in[14];
  const float* fb2    = (const float*)d_in[15];
  const float* ln2g   = (const float*)d_in[16];
  const float* ln2b   = (const float*)d_in[17];
  const float* fcw    = (const float*)d_in[18];
  const float* fcb    = (const float*)d_in[19];
  float* out = (float*)d_out;

  char* ws = (char*)d_ws;
  size_t off = 0;
  auto alloc = [&](size_t bytes) -> void* {
    void* p = ws + off;
    off += (bytes + 255) & ~(size_t)255;
    return p;
  };
  u16*   xb    = (u16*)alloc((size_t)4096 * 512 * 2);
  float* xf    = (float*)alloc((size_t)4096 * 512 * 4);
  u16*   qkv1b = (u16*)alloc((size_t)4096 * 1536 * 2);   // + at1 reused as pO
  u16*   at1   = (u16*)alloc((size_t)4096 * 512 * 2);
  u16*   cab   = (u16*)alloc((size_t)4096 * 512 * 2);
  u16*   qkv2  = (u16*)alloc((size_t)4096 * 1536 * 2);
  u16*   at2   = (u16*)alloc((size_t)4096 * 512 * 2);
  float* gaf   = (float*)alloc((size_t)4096 * 512 * 4);
  float* x1f   = (float*)alloc((size_t)4096 * 512 * 4);
  u16*   x1b   = (u16*)alloc((size_t)4096 * 512 * 2);
  u16*   f1b   = (u16*)alloc((size_t)4096 * 2048 * 2);
  float* ff    = (float*)alloc((size_t)4096 * 512 * 4);
  u16*   x2b   = (u16*)alloc((size_t)4096 * 512 * 2);
  u16*   wcinb  = (u16*)alloc((size_t)1536 * 512 * 2);
  u16*   wcoutb = (u16*)alloc((size_t)512 * 512 * 2);
  u16*   wginb  = (u16*)alloc((size_t)1536 * 512 * 2);
  u16*   wgoutb = (u16*)alloc((size_t)512 * 512 * 2);
  u16*   wf1b   = (u16*)alloc((size_t)2048 * 512 * 2);
  u16*   wf2b   = (u16*)alloc((size_t)512 * 2048 * 2);
  u16*   wfcb   = (u16*)alloc((size_t)32000 * 512 * 2);

  // temporal aliases (dead by the global-attention stage)
  float* pO = (float*)qkv1b;       // 2 x 4096 x 512 f32 = 16 MB (qkv1b 12MB + at1 4MB)
  float* pm = (float*)xb;          // 2 x 8 x 4096 f32
  float* pl = pm + 2 * 8 * 4096;

  // fused embed+PE | weight conversion
  prep<<<4096 + 2048, 256, 0, stream>>>(
      tokens, emb, xf, xb,
      (const float4*)cwin, wcinb, (const float4*)cwout, wcoutb,
      (const float4*)gwin, wginb, (const float4*)gwout, wgoutb,
      (const float4*)fw1, wf1b, (const float4*)fw2, wf2b,
      (const float4*)fcw, wfcb);

  // chunk stage
  gemm_bt<64, 128, 0, 0, 1><<<768, 256, 0, stream>>>(xb, wcinb, cbin, (float*)nullptr, qkv1b, 4096, 1536, 512);
  chunk_attn<<<2048, 256, 0, stream>>>(qkv1b, at1);
  gemm_bt<64, 64, 0, 0, 1><<<512, 256, 0, stream>>>(at1, wcoutb, cbout, (float*)nullptr, cab, 4096, 512, 512);

  // global stage
  gemm_bt<64, 128, 0, 0, 1><<<768, 256, 0, stream>>>(cab, wginb, gbin, (float*)nullptr, qkv2, 4096, 1536, 512);
  flash_attn<<<dim3(32, 8, 2), 512, 0, stream>>>(qkv2, pO, pm, pl);
  attn_merge<<<1024, 256, 0, stream>>>(pO, pm, pl, at2);
  gemm_bt<64, 64, 0, 1, 0><<<512, 256, 0, stream>>>(at2, wgoutb, gbout, gaf, (u16*)nullptr, 4096, 512, 512);

  // post-norm encoder layer
  add_ln<1><<<1024, 256, 0, stream>>>(xf, gaf, ln1g, ln1b, x1f, x1b);
  gemm_bt<64, 128, 1, 0, 1><<<1024, 256, 0, stream>>>(x1b, wf1b, fb1, (float*)nullptr, f1b, 4096, 2048, 512);
  gemm_bt<64, 64, 0, 1, 0><<<512, 256, 0, stream>>>(f1b, wf2b, fb2, ff, (u16*)nullptr, 4096, 512, 2048);
  add_ln<0><<<1024, 256, 0, stream>>>(x1f, ff, ln2g, ln2b, (float*)nullptr, x2b);

  // vocab projection: 2000-block 256^2 pipeline, split-phase nt epilogue
  gemm256<512><<<2000, 512, 0, stream>>>(x2b, wfcb, fcb, out, 4096, 32000);
}